// Round 5
// baseline (272.101 us; speedup 1.0000x reference)
//
#include <hip/hip_runtime.h>
#include <hip/hip_bf16.h>

// Problem dims
constexpr int B   = 2;
constexpr int HH  = 7;    // history turns
constexpr int H   = 8;    // total turns
constexpr int L   = 256;
constexpr int C   = 512;
constexpr int NH  = 8;
constexpr int DH  = 64;
constexpr int KS  = 4;    // top-k slots
constexpr int BH  = B * H;          // 16
constexpr int M4  = B * H * L;      // 4096 rows
constexpr size_t S = (size_t)B * H * L * C;  // 2,097,152 elems

typedef __attribute__((ext_vector_type(8))) short short8;
typedef __attribute__((ext_vector_type(4))) float f32x4;
typedef unsigned short u16;
typedef unsigned int u32;

__device__ inline float bf2f(u16 u) {
    u32 x = ((u32)u) << 16;
    return __uint_as_float(x);
}
__device__ inline u16 f2bf(float f) {
    __hip_bfloat16 h = __float2bfloat16(f);
    return *reinterpret_cast<u16*>(&h);
}
__device__ inline u32 packbf(float lo, float hi) {
    return ((u32)f2bf(hi) << 16) | (u32)f2bf(lo);
}
__device__ inline void gload16(const void* g, void* l) {
    __builtin_amdgcn_global_load_lds(
        (const __attribute__((address_space(1))) void*)g,
        (__attribute__((address_space(3))) void*)l,
        16, 0, 0);
}
__device__ inline void vmcnt0() {
    asm volatile("s_waitcnt vmcnt(0)" ::: "memory");
}

// ------------------------------------------------- concat ctx (+bf16 cast)
__global__ __launch_bounds__(256) void concat_cast_kernel(
    const float* __restrict__ hist, const float* __restrict__ cur,
    float* __restrict__ ctx, u16* __restrict__ Xb)
{
    size_t i4 = (size_t)blockIdx.x * 256 + threadIdx.x;
    size_t elem = i4 * 4;
    int c  = (int)(elem & (C - 1));
    size_t rest = elem >> 9;
    int l  = (int)(rest & (L - 1));
    int bh = (int)(rest >> 8);
    int h  = bh & (H - 1);
    int b  = bh >> 3;
    float4 v;
    if (h < HH) {
        size_t off = ((((size_t)b * HH + h) * L + l) * C + c);
        v = *reinterpret_cast<const float4*>(hist + off);
    } else {
        size_t off = (((size_t)b * L + l) * C + c);
        v = *reinterpret_cast<const float4*>(cur + off);
    }
    *reinterpret_cast<float4*>(ctx + elem) = v;
    ushort4 o;
    o.x = f2bf(v.x); o.y = f2bf(v.y); o.z = f2bf(v.z); o.w = f2bf(v.w);
    *reinterpret_cast<ushort4*>(Xb + elem) = o;
}

// ---------------------------------------------------------------- topk+softmax
__global__ void topk_kernel(const float* __restrict__ gmap,
                            float* __restrict__ attnw,
                            int* __restrict__ indxO,
                            int* __restrict__ expertO)
{
    int t = threadIdx.x;
    if (t >= BH) return;
    int h = t & (H - 1);
    const float* row = gmap + (size_t)t * H;
    float v[H];
    #pragma unroll
    for (int j = 0; j < H; ++j) v[j] = row[j];
    float sel[KS]; int si[KS];
    #pragma unroll
    for (int kk = 0; kk < KS; ++kk) {
        float best = -1e30f; int bi = 0;
        #pragma unroll
        for (int j = 0; j < H; ++j) {
            if (v[j] > best) { best = v[j]; bi = j; }
        }
        sel[kk] = best; si[kk] = bi; v[bi] = -1e30f;
    }
    float mx = sel[0];
    float w[KS]; float sum = 0.f;
    #pragma unroll
    for (int kk = 0; kk < KS; ++kk) { w[kk] = __expf(sel[kk] - mx); sum += w[kk]; }
    float inv = 1.f / sum;
    #pragma unroll
    for (int kk = 0; kk < KS; ++kk) {
        attnw[t * KS + kk] = w[kk] * inv;
        indxO[t * KS + kk] = si[kk];
        int e = (si[kk] == h) ? 0 : ((si[kk] > h) ? 2 : 1);
        expertO[t * KS + kk] = e;
    }
}

// ---------------------------------------------------------------- combined bias
__global__ __launch_bounds__(256) void biasc_kernel(
    const float* __restrict__ bo,
    const float* __restrict__ attnw, const int* __restrict__ expertArr,
    float* __restrict__ biasC)
{
    int bh = blockIdx.x;
    float a[KS]; int e[KS];
    #pragma unroll
    for (int k = 0; k < KS; ++k) {
        a[k] = attnw[bh * KS + k];
        e[k] = expertArr[bh * KS + k];
    }
    #pragma unroll
    for (int it = 0; it < 2; ++it) {
        int c = threadIdx.x + it * 256;
        float s = 0.f;
        #pragma unroll
        for (int k = 0; k < KS; ++k)
            s += a[k] * bo[(size_t)e[k] * C + c];
        biasC[(size_t)bh * C + c] = s;
    }
}

// ---------------------------------------------------------------- weight casts
__global__ __launch_bounds__(256) void cast_w_kernel(
    const float* __restrict__ Wq, const float* __restrict__ Wk,
    const float* __restrict__ Wv, u16* __restrict__ Wt)
{
    int p = blockIdx.z;
    int e = p / 3, t = p % 3;
    const float* W = (t == 0 ? Wq : (t == 1 ? Wk : Wv)) + (size_t)e * C * C;
    __shared__ float tile[32][33];
    int k0 = blockIdx.y * 32, n0 = blockIdx.x * 32;
    int tc = threadIdx.x & 31, tr = threadIdx.x >> 5;
    #pragma unroll
    for (int i = 0; i < 4; ++i) {
        int r = tr + i * 8;
        tile[r][tc] = W[(size_t)(k0 + r) * C + n0 + tc];
    }
    __syncthreads();
    #pragma unroll
    for (int i = 0; i < 4; ++i) {
        int r = tr + i * 8;
        Wt[(size_t)p * C * C + (size_t)(n0 + r) * C + k0 + tc] = f2bf(tile[tc][r]);
    }
}

__global__ __launch_bounds__(256) void cast_wo_kernel(
    const float* __restrict__ Wo, u16* __restrict__ Wot)
{
    int p = blockIdx.z;
    const float* W = Wo + (size_t)p * C * C;
    __shared__ float tile[32][33];
    int k0 = blockIdx.y * 32, n0 = blockIdx.x * 32;
    int tc = threadIdx.x & 31, tr = threadIdx.x >> 5;
    #pragma unroll
    for (int i = 0; i < 4; ++i) {
        int r = tr + i * 8;
        tile[r][tc] = W[(size_t)(k0 + r) * C + n0 + tc];
    }
    __syncthreads();
    #pragma unroll
    for (int i = 0; i < 4; ++i) {
        int r = tr + i * 8;
        Wot[(size_t)p * C * C + (size_t)(n0 + r) * C + k0 + tc] = f2bf(tile[tc][r]);
    }
}

// ---------------------------------------------------------------- QKV proj MFMA (2-phase dbuf)
__global__ __launch_bounds__(256) void proj_mfma(
    const u16* __restrict__ Xb, const u16* __restrict__ Wt,
    const float* __restrict__ bq, const float* __restrict__ bk,
    const float* __restrict__ bv,
    u16* __restrict__ out)
{
    constexpr int BK = 64;
    int p = blockIdx.z;
    int e = p / 3, t = p % 3;
    const float* bias = (t == 0 ? bq : (t == 1 ? bk : bv)) + (size_t)e * C;
    u16* Y = out + (size_t)p * S;
    const u16* Wp = Wt + (size_t)p * C * C;

    int m0 = blockIdx.y * 128;
    int n0 = blockIdx.x * 128;

    __shared__ u16 As[2][128 * BK];
    __shared__ u16 Bs[2][128 * BK];

    int tid  = threadIdx.x;
    int lane = tid & 63;
    int wid  = tid >> 6;
    int wr = wid >> 1, wc = wid & 1;

    f32x4 acc[4][4];
    #pragma unroll
    for (int m = 0; m < 4; ++m)
        #pragma unroll
        for (int n = 0; n < 4; ++n)
            acc[m][n] = (f32x4){0.f, 0.f, 0.f, 0.f};

    int rowA = wr * 64 + (lane & 15);
    int rowB = wc * 64 + (lane & 15);
    int kgrp = 8 * (lane >> 4);

    auto stage = [&](int bb, int kt) {
        int k0 = kt * BK;
        #pragma unroll
        for (int j = 0; j < 4; ++j) {
            int chunk = (wid * 4 + j) * 64 + lane;
            int r = chunk >> 3;
            int k = (chunk & 7) << 3;
            gload16(Xb + (size_t)(m0 + r) * C + k0 + k, &As[bb][(wid * 4 + j) * 512]);
            gload16(Wp + (size_t)(n0 + r) * C + k0 + k, &Bs[bb][(wid * 4 + j) * 512]);
        }
    };

    stage(0, 0);
    vmcnt0();
    __syncthreads();

    for (int kt = 0; kt < C / BK; ++kt) {
        int bb = kt & 1;
        if (kt + 1 < C / BK) stage(bb ^ 1, kt + 1);
        #pragma unroll
        for (int ks = 0; ks < 2; ++ks) {
            int kb = ks * 32 + kgrp;
            short8 af[4], bfr[4];
            #pragma unroll
            for (int m = 0; m < 4; ++m)
                af[m] = *reinterpret_cast<const short8*>(&As[bb][(rowA + m * 16) * BK + kb]);
            #pragma unroll
            for (int n = 0; n < 4; ++n)
                bfr[n] = *reinterpret_cast<const short8*>(&Bs[bb][(rowB + n * 16) * BK + kb]);
            #pragma unroll
            for (int m = 0; m < 4; ++m)
                #pragma unroll
                for (int n = 0; n < 4; ++n)
                    acc[m][n] = __builtin_amdgcn_mfma_f32_16x16x32_bf16(
                        af[m], bfr[n], acc[m][n], 0, 0, 0);
        }
        if (kt + 1 < C / BK) {
            vmcnt0();
            __syncthreads();
        }
    }

    int colb = n0 + wc * 64 + (lane & 15);
    int rowb = m0 + wr * 64 + (lane >> 4) * 4;
    #pragma unroll
    for (int n = 0; n < 4; ++n) {
        int col = colb + n * 16;
        float bcol = bias[col];
        #pragma unroll
        for (int m = 0; m < 4; ++m) {
            #pragma unroll
            for (int r = 0; r < 4; ++r) {
                int row = rowb + m * 16 + r;
                Y[(size_t)row * C + col] = f2bf(acc[m][n][r] + bcol);
            }
        }
    }
}

// ---------------------------------------------------------------- MFMA flash attention
__global__ __launch_bounds__(256) void attn_mfma(
    const u16* __restrict__ qkv,
    const int* __restrict__ indx, const int* __restrict__ expertArr,
    const float* __restrict__ attnw,
    u16* __restrict__ Obuf)
{
    int head = blockIdx.x;
    int slot = blockIdx.y;
    int z    = blockIdx.z;
    int bh   = z >> 1, qh = z & 1;
    int b    = bh >> 3;
    int mi   = bh * KS + slot;
    int src  = indx[mi];
    int e    = expertArr[mi];
    float ak = attnw[mi];
    int qbase = qh * 128;

    const u16* qp = qkv + (size_t)(e * 3 + 0) * S + (size_t)bh * L * C + head * DH;
    const u16* kp = qkv + (size_t)(e * 3 + 1) * S + (size_t)(b * H + src) * L * C + head * DH;
    const u16* vp = qkv + (size_t)(e * 3 + 2) * S + (size_t)(b * H + src) * L * C + head * DH;

    __shared__ u16 Ks[64 * 64];
    __shared__ u16 Vt[64 * 64];
    __shared__ u16 Pl[4][32 * 64];

    int tid = threadIdx.x, lane = tid & 63, w = tid >> 6;
    int c = lane & 15, gl = lane >> 4;
    int qoff = qbase + w * 32;

    short8 qf[2][2];
    #pragma unroll
    for (int n = 0; n < 2; ++n)
        #pragma unroll
        for (int kf = 0; kf < 2; ++kf)
            qf[n][kf] = *reinterpret_cast<const short8*>(
                qp + (size_t)(qoff + n * 16 + c) * C + kf * 32 + 8 * gl);

    f32x4 accO[4][2];
    #pragma unroll
    for (int m = 0; m < 4; ++m)
        #pragma unroll
        for (int n = 0; n < 2; ++n)
            accO[m][n] = (f32x4){0.f, 0.f, 0.f, 0.f};
    float mrun[2], lrun[2];
    #pragma unroll
    for (int n = 0; n < 2; ++n) { mrun[n] = -1e30f; lrun[n] = 0.f; }

    char* Plw = (char*)&Pl[w][0];

    for (int t = 0; t < 4; ++t) {
        int c0 = t * 64;
        __syncthreads();
        #pragma unroll
        for (int it = 0; it < 2; ++it) {
            int ch = tid + 256 * it;
            int r = ch >> 3, cb = ch & 7;
            short8 kv = *reinterpret_cast<const short8*>(kp + (size_t)(c0 + r) * C + cb * 8);
            int ad = (r * 128 + cb * 16) ^ ((r & 7) << 4);
            *reinterpret_cast<short8*>((char*)Ks + ad) = kv;
        }
        {
            int rp = tid & 31;
            int d0 = (tid >> 5) * 8;
            const u16* v0p = vp + (size_t)(c0 + 2 * rp) * C + d0;
            const u16* v1p = v0p + C;
            ushort4 a0 = *reinterpret_cast<const ushort4*>(v0p);
            ushort4 a1 = *reinterpret_cast<const ushort4*>(v0p + 4);
            ushort4 b0 = *reinterpret_cast<const ushort4*>(v1p);
            ushort4 b1 = *reinterpret_cast<const ushort4*>(v1p + 4);
            u16 va[8] = {a0.x, a0.y, a0.z, a0.w, a1.x, a1.y, a1.z, a1.w};
            u16 vb[8] = {b0.x, b0.y, b0.z, b0.w, b1.x, b1.y, b1.z, b1.w};
            #pragma unroll
            for (int j = 0; j < 8; ++j) {
                u32 pk = ((u32)vb[j] << 16) | (u32)va[j];
                int ad = ((d0 + j) * 128 + rp * 4) ^ (((d0 + j) & 7) << 4);
                *reinterpret_cast<u32*>((char*)Vt + ad) = pk;
            }
        }
        __syncthreads();

        f32x4 accS[4][2];
        #pragma unroll
        for (int m = 0; m < 4; ++m)
            #pragma unroll
            for (int n = 0; n < 2; ++n)
                accS[m][n] = (f32x4){0.f, 0.f, 0.f, 0.f};
        #pragma unroll
        for (int kf = 0; kf < 2; ++kf) {
            short8 ka[4];
            #pragma unroll
            for (int m = 0; m < 4; ++m) {
                int row = m * 16 + c;
                ka[m] = *reinterpret_cast<const short8*>(
                    (char*)Ks + ((row * 128 + (kf * 32 + 8 * gl) * 2) ^ ((row & 7) << 4)));
            }
            #pragma unroll
            for (int m = 0; m < 4; ++m)
                #pragma unroll
                for (int n = 0; n < 2; ++n)
                    accS[m][n] = __builtin_amdgcn_mfma_f32_16x16x32_bf16(
                        ka[m], qf[n][kf], accS[m][n], 0, 0, 0);
        }

        #pragma unroll
        for (int n = 0; n < 2; ++n) {
            float tm = -1e30f;
            #pragma unroll
            for (int m = 0; m < 4; ++m)
                #pragma unroll
                for (int r = 0; r < 4; ++r)
                    tm = fmaxf(tm, accS[m][n][r] * 0.125f);
            tm = fmaxf(tm, __shfl_xor(tm, 16));
            tm = fmaxf(tm, __shfl_xor(tm, 32));
            float nm = fmaxf(mrun[n], tm);
            float al = __expf(mrun[n] - nm);
            mrun[n] = nm;
            lrun[n] *= al;
            #pragma unroll
            for (int m = 0; m < 4; ++m)
                #pragma unroll
                for (int r = 0; r < 4; ++r)
                    accO[m][n][r] *= al;
            float ps = 0.f;
            #pragma unroll
            for (int m = 0; m < 4; ++m)
                #pragma unroll
                for (int r = 0; r < 4; ++r) {
                    float pv = __expf(accS[m][n][r] * 0.125f - nm);
                    accS[m][n][r] = pv;
                    ps += pv;
                }
            lrun[n] += ps;
            int row = n * 16 + c;
            int sw = (row & 7) << 4;
            #pragma unroll
            for (int m = 0; m < 4; ++m) {
                u32 p0 = packbf(accS[m][n][0], accS[m][n][1]);
                u32 p1 = packbf(accS[m][n][2], accS[m][n][3]);
                int base = row * 128 + (m * 16 + 4 * gl) * 2;
                *reinterpret_cast<u32*>(Plw + (base ^ sw)) = p0;
                *reinterpret_cast<u32*>(Plw + ((base + 4) ^ sw)) = p1;
            }
        }

        #pragma unroll
        for (int kf = 0; kf < 2; ++kf) {
            short8 va[4], pb[2];
            #pragma unroll
            for (int m = 0; m < 4; ++m) {
                int row = m * 16 + c;
                va[m] = *reinterpret_cast<const short8*>(
                    (char*)Vt + ((row * 128 + (kf * 32 + 8 * gl) * 2) ^ ((row & 7) << 4)));
            }
            #pragma unroll
            for (int n = 0; n < 2; ++n) {
                int row = n * 16 + c;
                pb[n] = *reinterpret_cast<const short8*>(
                    Plw + ((row * 128 + (kf * 32 + 8 * gl) * 2) ^ ((row & 7) << 4)));
            }
            #pragma unroll
            for (int m = 0; m < 4; ++m)
                #pragma unroll
                for (int n = 0; n < 2; ++n)
                    accO[m][n] = __builtin_amdgcn_mfma_f32_16x16x32_bf16(
                        va[m], pb[n], accO[m][n], 0, 0, 0);
        }
    }

    float inv[2];
    #pragma unroll
    for (int n = 0; n < 2; ++n) {
        float lv = lrun[n];
        lv += __shfl_xor(lv, 16);
        lv += __shfl_xor(lv, 32);
        inv[n] = ak / lv;     // fold a_k into O
    }
    #pragma unroll
    for (int m = 0; m < 4; ++m)
        #pragma unroll
        for (int n = 0; n < 2; ++n) {
            int row = n * 16 + c;
            int sw = (row & 7) << 4;
            float o0 = accO[m][n][0] * inv[n];
            float o1 = accO[m][n][1] * inv[n];
            float o2 = accO[m][n][2] * inv[n];
            float o3 = accO[m][n][3] * inv[n];
            int base = row * 128 + (m * 16 + 4 * gl) * 2;
            *reinterpret_cast<u32*>(Plw + (base ^ sw)) = packbf(o0, o1);
            *reinterpret_cast<u32*>(Plw + ((base + 4) ^ sw)) = packbf(o2, o3);
        }
    #pragma unroll
    for (int it = 0; it < 4; ++it) {
        int q = it * 8 + (lane >> 3), cb = lane & 7;
        short8 ov = *reinterpret_cast<const short8*>(
            Plw + ((q * 128 + cb * 16) ^ ((q & 7) << 4)));
        *reinterpret_cast<short8*>(
            Obuf + ((size_t)mi * L + qoff + q) * C + head * DH + cb * 8) = ov;
    }
}

// ---------------------------------------------------------------- Wo (slot-split, atomic combine, 2-phase dbuf)
__global__ __launch_bounds__(256) void wo_split_mfma(
    const u16* __restrict__ Obuf, const u16* __restrict__ Wot,
    const int* __restrict__ expertArr,
    float* __restrict__ wise)
{
    constexpr int BK = 64;
    int mi = blockIdx.z;
    int bh = mi >> 2;
    int e  = expertArr[mi];
    int m0 = blockIdx.y * 64;
    int n0 = blockIdx.x * 128;

    const u16* Ap = Obuf + (size_t)mi * L * C + (size_t)m0 * C;
    const u16* Bp = Wot + (size_t)e * C * C + (size_t)n0 * C;

    __shared__ u16 As[2][64 * BK];
    __shared__ u16 Bs[2][128 * BK];

    int tid = threadIdx.x, lane = tid & 63, wid = tid >> 6;
    int wr = wid >> 1, wc = wid & 1;
    int c = lane & 15, gl = lane >> 4;

    f32x4 acc[2][4];
    #pragma unroll
    for (int m = 0; m < 2; ++m)
        #pragma unroll
        for (int n = 0; n < 4; ++n)
            acc[m][n] = (f32x4){0.f, 0.f, 0.f, 0.f};

    auto stage = [&](int bb, int kt) {
        int k0 = kt * BK;
        #pragma unroll
        for (int it = 0; it < 2; ++it) {
            int base = wid * 64 + it * 256;
            int chunk = base + lane;
            int r = chunk >> 3;
            int kk = (chunk & 7) << 3;
            gload16(Ap + (size_t)r * C + k0 + kk, &As[bb][base * 8]);
        }
        #pragma unroll
        for (int j = 0; j < 4; ++j) {
            int base = (wid * 4 + j) * 64;
            int chunk = base + lane;
            int r = chunk >> 3;
            int kk = (chunk & 7) << 3;
            gload16(Bp + (size_t)r * C + k0 + kk, &Bs[bb][base * 8]);
        }
    };

    stage(0, 0);
    vmcnt0();
    __syncthreads();

    for (int kt = 0; kt < C / BK; ++kt) {
        int bb = kt & 1;
        if (kt + 1 < C / BK) stage(bb ^ 1, kt + 1);
        #pragma unroll
        for (int ks = 0; ks < 2; ++ks) {
            int kb = ks * 32 + 8 * gl;
            short8 af[2], bfr[4];
            #pragma unroll
            for (int m = 0; m < 2; ++m)
                af[m] = *reinterpret_cast<const short8*>(&As[bb][(wr * 32 + m * 16 + c) * BK + kb]);
            #pragma unroll
            for (int n = 0; n < 4; ++n)
                bfr[n] = *reinterpret_cast<const short8*>(&Bs[bb][(wc * 64 + n * 16 + c) * BK + kb]);
            #pragma unroll
            for (int m = 0; m < 2; ++m)
                #pragma unroll
                for (int n = 0; n < 4; ++n)
                    acc[m][n] = __builtin_amdgcn_mfma_f32_16x16x32_bf16(
                        af[m], bfr[n], acc[m][n], 0, 0, 0);
        }
        if (kt + 1 < C / BK) {
            vmcnt0();
            __syncthreads();
        }
    }

    float* wbh = wise + (size_t)bh * L * C;
    #pragma unroll
    for (int m = 0; m < 2; ++m) {
        #pragma unroll
        for (int r = 0; r < 4; ++r) {
            int row = m0 + wr * 32 + m * 16 + 4 * gl + r;
            #pragma unroll
            for (int n = 0; n < 4; ++n) {
                int col = n0 + wc * 64 + n * 16 + c;
                atomicAdd(&wbh[(size_t)row * C + col], acc[m][n][r]);
            }
        }
    }
}

// ---------------------------------------------------------------- relu + add (+bias, +bf16 cast)
__global__ __launch_bounds__(256) void ew_relu_add_cast(
    const float* __restrict__ wise, const float* __restrict__ biasC,
    const float* __restrict__ xin,
    float* __restrict__ xout, u16* __restrict__ Xb)
{
    size_t i4 = (size_t)blockIdx.x * 256 + threadIdx.x;
    size_t elem = i4 * 4;
    int cc = (int)(elem & (C - 1));
    int bh = (int)(elem >> 17);
    float4 w = *reinterpret_cast<const float4*>(wise + elem);
    float4 bsv = *reinterpret_cast<const float4*>(biasC + (size_t)bh * C + cc);
    float4 x = *reinterpret_cast<const float4*>(xin + elem);
    float4 o;
    o.x = fmaxf(w.x + bsv.x, 0.f) + x.x;
    o.y = fmaxf(w.y + bsv.y, 0.f) + x.y;
    o.z = fmaxf(w.z + bsv.z, 0.f) + x.z;
    o.w = fmaxf(w.w + bsv.w, 0.f) + x.w;
    *reinterpret_cast<float4*>(xout + elem) = o;
    ushort4 ob;
    ob.x = f2bf(o.x); ob.y = f2bf(o.y); ob.z = f2bf(o.z); ob.w = f2bf(o.w);
    *reinterpret_cast<ushort4*>(Xb + elem) = ob;
}

// ----------------------------------------------------------------------------
extern "C" void kernel_launch(void* const* d_in, const int* in_sizes, int n_in,
                              void* d_out, int out_size, void* d_ws, size_t ws_size,
                              hipStream_t stream) {
    const float* gmap = (const float*)d_in[0];
    const float* hist = (const float*)d_in[1];
    const float* cur  = (const float*)d_in[2];
    const float* Wq   = (const float*)d_in[6];
    const float* bq   = (const float*)d_in[7];
    const float* Wk   = (const float*)d_in[8];
    const float* bk   = (const float*)d_in[9];
    const float* Wv   = (const float*)d_in[10];
    const float* bv   = (const float*)d_in[11];
    const float* Wo   = (const float*)d_in[12];
    const float* bo   = (const float*)d_in[13];
    float* outp       = (float*)d_out;

    char* ws = (char*)d_ws;
    float* ctx  = (float*)(ws);                      // [0,4S)
    float* x1   = (float*)(ws + 4 * S);              // [4S,8S)
    float* wise = (float*)(ws + 8 * S);              // [8S,12S)
    u16*   qkv  = (u16*)(ws + 12 * S);               // [12S,30S)
    u16*   Obuf = (u16*)(ws + 30 * S);               // [30S,38S)
    char*  tail = ws + 38 * S;
    float* attnw  = (float*)(tail);                  // 256 B
    int*   indx   = (int*)(tail + 256);
    int*   expert = (int*)(tail + 512);
    float* biasC  = (float*)(tail + 1024);           // 32 KB
    u16*   Wot    = (u16*)(tail + 64 * 1024);        // 1.57 MB
    u16*   Xb     = (u16*)(tail + 2 * 1024 * 1024);  // 4 MB
    u16*   Wt     = (u16*)(tail + 8 * 1024 * 1024);  // 4.7 MB

    dim3 projGrid(C / 128, M4 / 128, 9);
    dim3 castWGrid(C / 32, C / 32, 9);
    dim3 castWoGrid(C / 32, C / 32, 3);
    dim3 attnGrid(NH, KS, BH * 2);
    dim3 woGrid(C / 128, L / 64, BH * KS);
    int ewBlocks = (int)(S / 4 / 256);   // 2048

    concat_cast_kernel<<<ewBlocks, 256, 0, stream>>>(hist, cur, ctx, Xb);
    topk_kernel<<<1, 64, 0, stream>>>(gmap, attnw, indx, expert);
    biasc_kernel<<<BH, 256, 0, stream>>>(bo, attnw, expert, biasC);
    cast_wo_kernel<<<castWoGrid, 256, 0, stream>>>(Wo, Wot);
    cast_w_kernel<<<castWGrid, 256, 0, stream>>>(Wq, Wk, Wv, Wt);

    // ---- layer 1: ctx -> x1
    proj_mfma<<<projGrid, 256, 0, stream>>>(Xb, Wt, bq, bk, bv, qkv);
    hipMemsetAsync(wise, 0, S * sizeof(float), stream);
    attn_mfma<<<attnGrid, 256, 0, stream>>>(qkv, indx, expert, attnw, Obuf);
    wo_split_mfma<<<woGrid, 256, 0, stream>>>(Obuf, Wot, expert, wise);
    ew_relu_add_cast<<<ewBlocks, 256, 0, stream>>>(wise, biasC, ctx, x1, Xb);

    // ---- layer 2: x1 -> out
    proj_mfma<<<projGrid, 256, 0, stream>>>(Xb, Wt, bq, bk, bv, qkv);
    hipMemsetAsync(wise, 0, S * sizeof(float), stream);
    attn_mfma<<<attnGrid, 256, 0, stream>>>(qkv, indx, expert, attnw, Obuf);
    wo_split_mfma<<<woGrid, 256, 0, stream>>>(Obuf, Wot, expert, wise);
    ew_relu_add_cast<<<ewBlocks, 256, 0, stream>>>(wise, biasC, x1, outp, Xb);
}

// Round 6
// 203.716 us; speedup vs baseline: 1.3357x; 1.3357x over previous
//
#include <hip/hip_runtime.h>
#include <hip/hip_bf16.h>

// Problem dims
constexpr int B   = 2;
constexpr int HH  = 7;    // history turns
constexpr int H   = 8;    // total turns
constexpr int L   = 256;
constexpr int C   = 512;
constexpr int NH  = 8;
constexpr int DH  = 64;
constexpr int KS  = 4;    // top-k slots
constexpr int BH  = B * H;          // 16
constexpr int M4  = B * H * L;      // 4096 rows
constexpr size_t S = (size_t)B * H * L * C;  // 2,097,152 elems

typedef __attribute__((ext_vector_type(8))) short short8;
typedef __attribute__((ext_vector_type(4))) float f32x4;
typedef unsigned short u16;
typedef unsigned int u32;

__device__ inline float bf2f(u16 u) {
    u32 x = ((u32)u) << 16;
    return __uint_as_float(x);
}
__device__ inline u16 f2bf(float f) {
    __hip_bfloat16 h = __float2bfloat16(f);
    return *reinterpret_cast<u16*>(&h);
}
__device__ inline u32 packbf(float lo, float hi) {
    return ((u32)f2bf(hi) << 16) | (u32)f2bf(lo);
}
__device__ inline void gload16(const void* g, void* l) {
    __builtin_amdgcn_global_load_lds(
        (const __attribute__((address_space(1))) void*)g,
        (__attribute__((address_space(3))) void*)l,
        16, 0, 0);
}
__device__ inline void vmcnt0() {
    asm volatile("s_waitcnt vmcnt(0)" ::: "memory");
}

// ------------------------------------------------- concat ctx (+bf16 cast)
__global__ __launch_bounds__(256) void concat_cast_kernel(
    const float* __restrict__ hist, const float* __restrict__ cur,
    float* __restrict__ ctx, u16* __restrict__ Xb)
{
    size_t i4 = (size_t)blockIdx.x * 256 + threadIdx.x;
    size_t elem = i4 * 4;
    int c  = (int)(elem & (C - 1));
    size_t rest = elem >> 9;
    int l  = (int)(rest & (L - 1));
    int bh = (int)(rest >> 8);
    int h  = bh & (H - 1);
    int b  = bh >> 3;
    float4 v;
    if (h < HH) {
        size_t off = ((((size_t)b * HH + h) * L + l) * C + c);
        v = *reinterpret_cast<const float4*>(hist + off);
    } else {
        size_t off = (((size_t)b * L + l) * C + c);
        v = *reinterpret_cast<const float4*>(cur + off);
    }
    *reinterpret_cast<float4*>(ctx + elem) = v;
    ushort4 o;
    o.x = f2bf(v.x); o.y = f2bf(v.y); o.z = f2bf(v.z); o.w = f2bf(v.w);
    *reinterpret_cast<ushort4*>(Xb + elem) = o;
}

// ---------------------------------------------------------------- topk+softmax
__global__ void topk_kernel(const float* __restrict__ gmap,
                            float* __restrict__ attnw,
                            int* __restrict__ indxO,
                            int* __restrict__ expertO)
{
    int t = threadIdx.x;
    if (t >= BH) return;
    int h = t & (H - 1);
    const float* row = gmap + (size_t)t * H;
    float v[H];
    #pragma unroll
    for (int j = 0; j < H; ++j) v[j] = row[j];
    float sel[KS]; int si[KS];
    #pragma unroll
    for (int kk = 0; kk < KS; ++kk) {
        float best = -1e30f; int bi = 0;
        #pragma unroll
        for (int j = 0; j < H; ++j) {
            if (v[j] > best) { best = v[j]; bi = j; }
        }
        sel[kk] = best; si[kk] = bi; v[bi] = -1e30f;
    }
    float mx = sel[0];
    float w[KS]; float sum = 0.f;
    #pragma unroll
    for (int kk = 0; kk < KS; ++kk) { w[kk] = __expf(sel[kk] - mx); sum += w[kk]; }
    float inv = 1.f / sum;
    #pragma unroll
    for (int kk = 0; kk < KS; ++kk) {
        attnw[t * KS + kk] = w[kk] * inv;
        indxO[t * KS + kk] = si[kk];
        int e = (si[kk] == h) ? 0 : ((si[kk] > h) ? 2 : 1);
        expertO[t * KS + kk] = e;
    }
}

// ---------------------------------------------------------------- combined bias
__global__ __launch_bounds__(256) void biasc_kernel(
    const float* __restrict__ bo,
    const float* __restrict__ attnw, const int* __restrict__ expertArr,
    float* __restrict__ biasC)
{
    int bh = blockIdx.x;
    float a[KS]; int e[KS];
    #pragma unroll
    for (int k = 0; k < KS; ++k) {
        a[k] = attnw[bh * KS + k];
        e[k] = expertArr[bh * KS + k];
    }
    #pragma unroll
    for (int it = 0; it < 2; ++it) {
        int c = threadIdx.x + it * 256;
        float s = 0.f;
        #pragma unroll
        for (int k = 0; k < KS; ++k)
            s += a[k] * bo[(size_t)e[k] * C + c];
        biasC[(size_t)bh * C + c] = s;
    }
}

// ---------------------------------------------------------------- weight casts
__global__ __launch_bounds__(256) void cast_w_kernel(
    const float* __restrict__ Wq, const float* __restrict__ Wk,
    const float* __restrict__ Wv, u16* __restrict__ Wt)
{
    int p = blockIdx.z;
    int e = p / 3, t = p % 3;
    const float* W = (t == 0 ? Wq : (t == 1 ? Wk : Wv)) + (size_t)e * C * C;
    __shared__ float tile[32][33];
    int k0 = blockIdx.y * 32, n0 = blockIdx.x * 32;
    int tc = threadIdx.x & 31, tr = threadIdx.x >> 5;
    #pragma unroll
    for (int i = 0; i < 4; ++i) {
        int r = tr + i * 8;
        tile[r][tc] = W[(size_t)(k0 + r) * C + n0 + tc];
    }
    __syncthreads();
    #pragma unroll
    for (int i = 0; i < 4; ++i) {
        int r = tr + i * 8;
        Wt[(size_t)p * C * C + (size_t)(n0 + r) * C + k0 + tc] = f2bf(tile[tc][r]);
    }
}

__global__ __launch_bounds__(256) void cast_wo_kernel(
    const float* __restrict__ Wo, u16* __restrict__ Wot)
{
    int p = blockIdx.z;
    const float* W = Wo + (size_t)p * C * C;
    __shared__ float tile[32][33];
    int k0 = blockIdx.y * 32, n0 = blockIdx.x * 32;
    int tc = threadIdx.x & 31, tr = threadIdx.x >> 5;
    #pragma unroll
    for (int i = 0; i < 4; ++i) {
        int r = tr + i * 8;
        tile[r][tc] = W[(size_t)(k0 + r) * C + n0 + tc];
    }
    __syncthreads();
    #pragma unroll
    for (int i = 0; i < 4; ++i) {
        int r = tr + i * 8;
        Wot[(size_t)p * C * C + (size_t)(n0 + r) * C + k0 + tc] = f2bf(tile[tc][r]);
    }
}

// ---------------------------------------------------------------- QKV proj MFMA
// single-buffer (R4 structure) + T2 swizzle: linear LDS dest, source chunk
// cb^=(r&7), reads ^((row&7)<<4)  [rule #21: both-sides-or-neither]
__global__ __launch_bounds__(256) void proj_mfma(
    const u16* __restrict__ Xb, const u16* __restrict__ Wt,
    const float* __restrict__ bq, const float* __restrict__ bk,
    const float* __restrict__ bv,
    u16* __restrict__ out)
{
    constexpr int BK = 64;
    int p = blockIdx.z;
    int e = p / 3, t = p % 3;
    const float* bias = (t == 0 ? bq : (t == 1 ? bk : bv)) + (size_t)e * C;
    u16* Y = out + (size_t)p * S;
    const u16* Wp = Wt + (size_t)p * C * C;

    int m0 = blockIdx.y * 128;
    int n0 = blockIdx.x * 128;

    __shared__ u16 As[128 * BK];
    __shared__ u16 Bs[128 * BK];

    int tid  = threadIdx.x;
    int lane = tid & 63;
    int wid  = tid >> 6;
    int wr = wid >> 1, wc = wid & 1;

    f32x4 acc[4][4];
    #pragma unroll
    for (int m = 0; m < 4; ++m)
        #pragma unroll
        for (int n = 0; n < 4; ++n)
            acc[m][n] = (f32x4){0.f, 0.f, 0.f, 0.f};

    int rowA = wr * 64 + (lane & 15);
    int rowB = wc * 64 + (lane & 15);
    int kgrp = 8 * (lane >> 4);

    for (int kt = 0; kt < C / BK; ++kt) {
        int k0 = kt * BK;
        #pragma unroll
        for (int j = 0; j < 4; ++j) {
            int chunk = (wid * 4 + j) * 64 + lane;
            int r  = chunk >> 3;
            int cb = chunk & 7;
            int ksw = (cb ^ (r & 7)) << 3;     // pre-swizzled source chunk
            gload16(Xb + (size_t)(m0 + r) * C + k0 + ksw, &As[(wid * 4 + j) * 512]);
            gload16(Wp + (size_t)(n0 + r) * C + k0 + ksw, &Bs[(wid * 4 + j) * 512]);
        }
        __syncthreads();
        const char* Ab = (const char*)As;
        const char* Bb = (const char*)Bs;
        #pragma unroll
        for (int ks = 0; ks < 2; ++ks) {
            int kb2 = (ks * 32 + kgrp) * 2;
            short8 af[4], bfr[4];
            #pragma unroll
            for (int m = 0; m < 4; ++m) {
                int row = rowA + m * 16;
                af[m] = *reinterpret_cast<const short8*>(
                    Ab + ((row * 128 + kb2) ^ ((row & 7) << 4)));
            }
            #pragma unroll
            for (int n = 0; n < 4; ++n) {
                int row = rowB + n * 16;
                bfr[n] = *reinterpret_cast<const short8*>(
                    Bb + ((row * 128 + kb2) ^ ((row & 7) << 4)));
            }
            #pragma unroll
            for (int m = 0; m < 4; ++m)
                #pragma unroll
                for (int n = 0; n < 4; ++n)
                    acc[m][n] = __builtin_amdgcn_mfma_f32_16x16x32_bf16(
                        af[m], bfr[n], acc[m][n], 0, 0, 0);
        }
        __syncthreads();
    }

    int colb = n0 + wc * 64 + (lane & 15);
    int rowb = m0 + wr * 64 + (lane >> 4) * 4;
    #pragma unroll
    for (int n = 0; n < 4; ++n) {
        int col = colb + n * 16;
        float bcol = bias[col];
        #pragma unroll
        for (int m = 0; m < 4; ++m) {
            #pragma unroll
            for (int r = 0; r < 4; ++r) {
                int row = rowb + m * 16 + r;
                Y[(size_t)row * C + col] = f2bf(acc[m][n][r] + bcol);
            }
        }
    }
}

// ---------------------------------------------------------------- MFMA flash attention
__global__ __launch_bounds__(256) void attn_mfma(
    const u16* __restrict__ qkv,
    const int* __restrict__ indx, const int* __restrict__ expertArr,
    const float* __restrict__ attnw,
    u16* __restrict__ Obuf)
{
    int head = blockIdx.x;
    int slot = blockIdx.y;
    int z    = blockIdx.z;
    int bh   = z >> 1, qh = z & 1;
    int b    = bh >> 3;
    int mi   = bh * KS + slot;
    int src  = indx[mi];
    int e    = expertArr[mi];
    float ak = attnw[mi];
    int qbase = qh * 128;

    const u16* qp = qkv + (size_t)(e * 3 + 0) * S + (size_t)bh * L * C + head * DH;
    const u16* kp = qkv + (size_t)(e * 3 + 1) * S + (size_t)(b * H + src) * L * C + head * DH;
    const u16* vp = qkv + (size_t)(e * 3 + 2) * S + (size_t)(b * H + src) * L * C + head * DH;

    __shared__ u16 Ks[64 * 64];
    __shared__ u16 Vt[64 * 64];
    __shared__ u16 Pl[4][32 * 64];

    int tid = threadIdx.x, lane = tid & 63, w = tid >> 6;
    int c = lane & 15, gl = lane >> 4;
    int qoff = qbase + w * 32;

    short8 qf[2][2];
    #pragma unroll
    for (int n = 0; n < 2; ++n)
        #pragma unroll
        for (int kf = 0; kf < 2; ++kf)
            qf[n][kf] = *reinterpret_cast<const short8*>(
                qp + (size_t)(qoff + n * 16 + c) * C + kf * 32 + 8 * gl);

    f32x4 accO[4][2];
    #pragma unroll
    for (int m = 0; m < 4; ++m)
        #pragma unroll
        for (int n = 0; n < 2; ++n)
            accO[m][n] = (f32x4){0.f, 0.f, 0.f, 0.f};
    float mrun[2], lrun[2];
    #pragma unroll
    for (int n = 0; n < 2; ++n) { mrun[n] = -1e30f; lrun[n] = 0.f; }

    char* Plw = (char*)&Pl[w][0];

    for (int t = 0; t < 4; ++t) {
        int c0 = t * 64;
        __syncthreads();
        #pragma unroll
        for (int it = 0; it < 2; ++it) {
            int ch = tid + 256 * it;
            int r = ch >> 3, cb = ch & 7;
            short8 kv = *reinterpret_cast<const short8*>(kp + (size_t)(c0 + r) * C + cb * 8);
            int ad = (r * 128 + cb * 16) ^ ((r & 7) << 4);
            *reinterpret_cast<short8*>((char*)Ks + ad) = kv;
        }
        {
            int rp = tid & 31;
            int d0 = (tid >> 5) * 8;
            const u16* v0p = vp + (size_t)(c0 + 2 * rp) * C + d0;
            const u16* v1p = v0p + C;
            ushort4 a0 = *reinterpret_cast<const ushort4*>(v0p);
            ushort4 a1 = *reinterpret_cast<const ushort4*>(v0p + 4);
            ushort4 b0 = *reinterpret_cast<const ushort4*>(v1p);
            ushort4 b1 = *reinterpret_cast<const ushort4*>(v1p + 4);
            u16 va[8] = {a0.x, a0.y, a0.z, a0.w, a1.x, a1.y, a1.z, a1.w};
            u16 vb[8] = {b0.x, b0.y, b0.z, b0.w, b1.x, b1.y, b1.z, b1.w};
            #pragma unroll
            for (int j = 0; j < 8; ++j) {
                u32 pk = ((u32)vb[j] << 16) | (u32)va[j];
                int ad = ((d0 + j) * 128 + rp * 4) ^ (((d0 + j) & 7) << 4);
                *reinterpret_cast<u32*>((char*)Vt + ad) = pk;
            }
        }
        __syncthreads();

        f32x4 accS[4][2];
        #pragma unroll
        for (int m = 0; m < 4; ++m)
            #pragma unroll
            for (int n = 0; n < 2; ++n)
                accS[m][n] = (f32x4){0.f, 0.f, 0.f, 0.f};
        #pragma unroll
        for (int kf = 0; kf < 2; ++kf) {
            short8 ka[4];
            #pragma unroll
            for (int m = 0; m < 4; ++m) {
                int row = m * 16 + c;
                ka[m] = *reinterpret_cast<const short8*>(
                    (char*)Ks + ((row * 128 + (kf * 32 + 8 * gl) * 2) ^ ((row & 7) << 4)));
            }
            #pragma unroll
            for (int m = 0; m < 4; ++m)
                #pragma unroll
                for (int n = 0; n < 2; ++n)
                    accS[m][n] = __builtin_amdgcn_mfma_f32_16x16x32_bf16(
                        ka[m], qf[n][kf], accS[m][n], 0, 0, 0);
        }

        #pragma unroll
        for (int n = 0; n < 2; ++n) {
            float tm = -1e30f;
            #pragma unroll
            for (int m = 0; m < 4; ++m)
                #pragma unroll
                for (int r = 0; r < 4; ++r)
                    tm = fmaxf(tm, accS[m][n][r] * 0.125f);
            tm = fmaxf(tm, __shfl_xor(tm, 16));
            tm = fmaxf(tm, __shfl_xor(tm, 32));
            float nm = fmaxf(mrun[n], tm);
            float al = __expf(mrun[n] - nm);
            mrun[n] = nm;
            lrun[n] *= al;
            #pragma unroll
            for (int m = 0; m < 4; ++m)
                #pragma unroll
                for (int r = 0; r < 4; ++r)
                    accO[m][n][r] *= al;
            float ps = 0.f;
            #pragma unroll
            for (int m = 0; m < 4; ++m)
                #pragma unroll
                for (int r = 0; r < 4; ++r) {
                    float pv = __expf(accS[m][n][r] * 0.125f - nm);
                    accS[m][n][r] = pv;
                    ps += pv;
                }
            lrun[n] += ps;
            int row = n * 16 + c;
            int sw = (row & 7) << 4;
            #pragma unroll
            for (int m = 0; m < 4; ++m) {
                u32 p0 = packbf(accS[m][n][0], accS[m][n][1]);
                u32 p1 = packbf(accS[m][n][2], accS[m][n][3]);
                int base = row * 128 + (m * 16 + 4 * gl) * 2;
                *reinterpret_cast<u32*>(Plw + (base ^ sw)) = p0;
                *reinterpret_cast<u32*>(Plw + ((base + 4) ^ sw)) = p1;
            }
        }

        #pragma unroll
        for (int kf = 0; kf < 2; ++kf) {
            short8 va[4], pb[2];
            #pragma unroll
            for (int m = 0; m < 4; ++m) {
                int row = m * 16 + c;
                va[m] = *reinterpret_cast<const short8*>(
                    (char*)Vt + ((row * 128 + (kf * 32 + 8 * gl) * 2) ^ ((row & 7) << 4)));
            }
            #pragma unroll
            for (int n = 0; n < 2; ++n) {
                int row = n * 16 + c;
                pb[n] = *reinterpret_cast<const short8*>(
                    Plw + ((row * 128 + (kf * 32 + 8 * gl) * 2) ^ ((row & 7) << 4)));
            }
            #pragma unroll
            for (int m = 0; m < 4; ++m)
                #pragma unroll
                for (int n = 0; n < 2; ++n)
                    accO[m][n] = __builtin_amdgcn_mfma_f32_16x16x32_bf16(
                        va[m], pb[n], accO[m][n], 0, 0, 0);
        }
    }

    float inv[2];
    #pragma unroll
    for (int n = 0; n < 2; ++n) {
        float lv = lrun[n];
        lv += __shfl_xor(lv, 16);
        lv += __shfl_xor(lv, 32);
        inv[n] = ak / lv;     // fold a_k into O
    }
    #pragma unroll
    for (int m = 0; m < 4; ++m)
        #pragma unroll
        for (int n = 0; n < 2; ++n) {
            int row = n * 16 + c;
            int sw = (row & 7) << 4;
            float o0 = accO[m][n][0] * inv[n];
            float o1 = accO[m][n][1] * inv[n];
            float o2 = accO[m][n][2] * inv[n];
            float o3 = accO[m][n][3] * inv[n];
            int base = row * 128 + (m * 16 + 4 * gl) * 2;
            *reinterpret_cast<u32*>(Plw + (base ^ sw)) = packbf(o0, o1);
            *reinterpret_cast<u32*>(Plw + ((base + 4) ^ sw)) = packbf(o2, o3);
        }
    #pragma unroll
    for (int it = 0; it < 4; ++it) {
        int q = it * 8 + (lane >> 3), cb = lane & 7;
        short8 ov = *reinterpret_cast<const short8*>(
            Plw + ((q * 128 + cb * 16) ^ ((q & 7) << 4)));
        *reinterpret_cast<short8*>(
            Obuf + ((size_t)mi * L + qoff + q) * C + head * DH + cb * 8) = ov;
    }
}

// ---------------------------------------------------------------- Wo fused-K GEMM
// wise[bh] = [a0 O0 | a1 O1 | a2 O2 | a3 O3] @ [W_e0; W_e1; W_e2; W_e3]
// (a_k already folded into Obuf by attn epilogue). K = 2048, 32 k-tiles.
// tile 64x128, 4 waves (2x2 of 32x64), 2-phase dbuf (grid = 1 block/CU so
// the extra LDS costs no occupancy), T2 source-preswizzled LDS.
__global__ __launch_bounds__(256) void wo_fused_mfma(
    const u16* __restrict__ Obuf, const u16* __restrict__ Wot,
    const int* __restrict__ expertArr,
    float* __restrict__ wise)
{
    constexpr int BK = 64;
    int bh = blockIdx.z;
    int m0 = blockIdx.y * 64;
    int n0 = blockIdx.x * 128;

    int e4[KS];
    #pragma unroll
    for (int k = 0; k < KS; ++k) e4[k] = expertArr[bh * KS + k];

    __shared__ u16 As[2][64 * BK];    // 2 x 8KB
    __shared__ u16 Bs[2][128 * BK];   // 2 x 16KB

    int tid = threadIdx.x, lane = tid & 63, wid = tid >> 6;
    int wr = wid >> 1, wc = wid & 1;
    int c = lane & 15, gl = lane >> 4;

    f32x4 acc[2][4];
    #pragma unroll
    for (int m = 0; m < 2; ++m)
        #pragma unroll
        for (int n = 0; n < 4; ++n)
            acc[m][n] = (f32x4){0.f, 0.f, 0.f, 0.f};

    auto stage = [&](int bb, int kt) {
        int slot = kt >> 3;
        int k0   = (kt & 7) * BK;
        const u16* Ap = Obuf + ((size_t)(bh * KS + slot) * L + m0) * C + k0;
        const u16* Bp = Wot + (size_t)e4[slot] * C * C + (size_t)n0 * C + k0;
        // A: 512 chunks, 2/thread
        #pragma unroll
        for (int it = 0; it < 2; ++it) {
            int base = wid * 64 + it * 256;
            int ch = base + lane;
            int r = ch >> 3, cb = ch & 7;
            int ksw = (cb ^ (r & 7)) << 3;
            gload16(Ap + (size_t)r * C + ksw, &As[bb][base * 8]);
        }
        // B: 1024 chunks, 4/thread
        #pragma unroll
        for (int j = 0; j < 4; ++j) {
            int base = (wid * 4 + j) * 64;
            int ch = base + lane;
            int r = ch >> 3, cb = ch & 7;
            int ksw = (cb ^ (r & 7)) << 3;
            gload16(Bp + (size_t)r * C + ksw, &Bs[bb][base * 8]);
        }
    };

    stage(0, 0);
    vmcnt0();
    __syncthreads();

    constexpr int NT = 4 * (C / BK);   // 32 k-tiles
    for (int kt = 0; kt < NT; ++kt) {
        int bb = kt & 1;
        if (kt + 1 < NT) stage(bb ^ 1, kt + 1);
        const char* Ab = (const char*)&As[bb][0];
        const char* Bb = (const char*)&Bs[bb][0];
        #pragma unroll
        for (int ks = 0; ks < 2; ++ks) {
            int kb2 = (ks * 32 + 8 * gl) * 2;
            short8 af[2], bfr[4];
            #pragma unroll
            for (int m = 0; m < 2; ++m) {
                int row = wr * 32 + m * 16 + c;
                af[m] = *reinterpret_cast<const short8*>(
                    Ab + ((row * 128 + kb2) ^ ((row & 7) << 4)));
            }
            #pragma unroll
            for (int n = 0; n < 4; ++n) {
                int row = wc * 64 + n * 16 + c;
                bfr[n] = *reinterpret_cast<const short8*>(
                    Bb + ((row * 128 + kb2) ^ ((row & 7) << 4)));
            }
            #pragma unroll
            for (int m = 0; m < 2; ++m)
                #pragma unroll
                for (int n = 0; n < 4; ++n)
                    acc[m][n] = __builtin_amdgcn_mfma_f32_16x16x32_bf16(
                        af[m], bfr[n], acc[m][n], 0, 0, 0);
        }
        if (kt + 1 < NT) {
            vmcnt0();
            __syncthreads();
        }
    }

    float* wbh = wise + (size_t)bh * L * C;
    #pragma unroll
    for (int m = 0; m < 2; ++m) {
        #pragma unroll
        for (int r = 0; r < 4; ++r) {
            int row = m0 + wr * 32 + m * 16 + 4 * gl + r;
            #pragma unroll
            for (int n = 0; n < 4; ++n) {
                int col = n0 + wc * 64 + n * 16 + c;
                wbh[(size_t)row * C + col] = acc[m][n][r];
            }
        }
    }
}

// ---------------------------------------------------------------- relu + add (+bias, +bf16 cast)
__global__ __launch_bounds__(256) void ew_relu_add_cast(
    const float* __restrict__ wise, const float* __restrict__ biasC,
    const float* __restrict__ xin,
    float* __restrict__ xout, u16* __restrict__ Xb)
{
    size_t i4 = (size_t)blockIdx.x * 256 + threadIdx.x;
    size_t elem = i4 * 4;
    int cc = (int)(elem & (C - 1));
    int bh = (int)(elem >> 17);
    float4 w = *reinterpret_cast<const float4*>(wise + elem);
    float4 bsv = *reinterpret_cast<const float4*>(biasC + (size_t)bh * C + cc);
    float4 x = *reinterpret_cast<const float4*>(xin + elem);
    float4 o;
    o.x = fmaxf(w.x + bsv.x, 0.f) + x.x;
    o.y = fmaxf(w.y + bsv.y, 0.f) + x.y;
    o.z = fmaxf(w.z + bsv.z, 0.f) + x.z;
    o.w = fmaxf(w.w + bsv.w, 0.f) + x.w;
    *reinterpret_cast<float4*>(xout + elem) = o;
    ushort4 ob;
    ob.x = f2bf(o.x); ob.y = f2bf(o.y); ob.z = f2bf(o.z); ob.w = f2bf(o.w);
    *reinterpret_cast<ushort4*>(Xb + elem) = ob;
}

// ----------------------------------------------------------------------------
extern "C" void kernel_launch(void* const* d_in, const int* in_sizes, int n_in,
                              void* d_out, int out_size, void* d_ws, size_t ws_size,
                              hipStream_t stream) {
    const float* gmap = (const float*)d_in[0];
    const float* hist = (const float*)d_in[1];
    const float* cur  = (const float*)d_in[2];
    const float* Wq   = (const float*)d_in[6];
    const float* bq   = (const float*)d_in[7];
    const float* Wk   = (const float*)d_in[8];
    const float* bk   = (const float*)d_in[9];
    const float* Wv   = (const float*)d_in[10];
    const float* bv   = (const float*)d_in[11];
    const float* Wo   = (const float*)d_in[12];
    const float* bo   = (const float*)d_in[13];
    float* outp       = (float*)d_out;

    char* ws = (char*)d_ws;
    float* ctx  = (float*)(ws);                      // [0,4S)
    float* x1   = (float*)(ws + 4 * S);              // [4S,8S)
    float* wise = (float*)(ws + 8 * S);              // [8S,12S)
    u16*   qkv  = (u16*)(ws + 12 * S);               // [12S,30S)
    u16*   Obuf = (u16*)(ws + 30 * S);               // [30S,38S)
    char*  tail = ws + 38 * S;
    float* attnw  = (float*)(tail);                  // 256 B
    int*   indx   = (int*)(tail + 256);
    int*   expert = (int*)(tail + 512);
    float* biasC  = (float*)(tail + 1024);           // 32 KB
    u16*   Wot    = (u16*)(tail + 64 * 1024);        // 1.57 MB
    u16*   Xb     = (u16*)(tail + 2 * 1024 * 1024);  // 4 MB
    u16*   Wt     = (u16*)(tail + 8 * 1024 * 1024);  // 4.7 MB

    dim3 projGrid(C / 128, M4 / 128, 9);
    dim3 castWGrid(C / 32, C / 32, 9);
    dim3 castWoGrid(C / 32, C / 32, 3);
    dim3 attnGrid(NH, KS, BH * 2);
    dim3 woGrid(C / 128, L / 64, BH);                // 4 x 4 x 16 = 256 blocks
    int ewBlocks = (int)(S / 4 / 256);   // 2048

    concat_cast_kernel<<<ewBlocks, 256, 0, stream>>>(hist, cur, ctx, Xb);
    topk_kernel<<<1, 64, 0, stream>>>(gmap, attnw, indx, expert);
    biasc_kernel<<<BH, 256, 0, stream>>>(bo, attnw, expert, biasC);
    cast_wo_kernel<<<castWoGrid, 256, 0, stream>>>(Wo, Wot);
    cast_w_kernel<<<castWGrid, 256, 0, stream>>>(Wq, Wk, Wv, Wt);

    // ---- layer 1: ctx -> x1
    proj_mfma<<<projGrid, 256, 0, stream>>>(Xb, Wt, bq, bk, bv, qkv);
    attn_mfma<<<attnGrid, 256, 0, stream>>>(qkv, indx, expert, attnw, Obuf);
    wo_fused_mfma<<<woGrid, 256, 0, stream>>>(Obuf, Wot, expert, wise);
    ew_relu_add_cast<<<ewBlocks, 256, 0, stream>>>(wise, biasC, ctx, x1, Xb);

    // ---- layer 2: x1 -> out
    proj_mfma<<<projGrid, 256, 0, stream>>>(Xb, Wt, bq, bk, bv, qkv);
    attn_mfma<<<attnGrid, 256, 0, stream>>>(qkv, indx, expert, attnw, Obuf);
    wo_fused_mfma<<<woGrid, 256, 0, stream>>>(Obuf, Wot, expert, wise);
    ew_relu_add_cast<<<ewBlocks, 256, 0, stream>>>(wise, biasC, x1, outp, Xb);
}

// Round 7
// 187.394 us; speedup vs baseline: 1.4520x; 1.0871x over previous
//
#include <hip/hip_runtime.h>
#include <hip/hip_bf16.h>

// Problem dims
constexpr int B   = 2;
constexpr int HH  = 7;    // history turns
constexpr int H   = 8;    // total turns
constexpr int L   = 256;
constexpr int C   = 512;
constexpr int NH  = 8;
constexpr int DH  = 64;
constexpr int KS  = 4;    // top-k slots
constexpr int BH  = B * H;          // 16
constexpr int M4  = B * H * L;      // 4096 rows
constexpr size_t S = (size_t)B * H * L * C;  // 2,097,152 elems

typedef __attribute__((ext_vector_type(8))) short short8;
typedef __attribute__((ext_vector_type(4))) float f32x4;
typedef unsigned short u16;
typedef unsigned int u32;

__device__ inline float bf2f(u16 u) {
    u32 x = ((u32)u) << 16;
    return __uint_as_float(x);
}
__device__ inline u16 f2bf(float f) {
    __hip_bfloat16 h = __float2bfloat16(f);
    return *reinterpret_cast<u16*>(&h);
}
__device__ inline u32 packbf(float lo, float hi) {
    return ((u32)f2bf(hi) << 16) | (u32)f2bf(lo);
}
__device__ inline void gload16(const void* g, void* l) {
    __builtin_amdgcn_global_load_lds(
        (const __attribute__((address_space(1))) void*)g,
        (__attribute__((address_space(3))) void*)l,
        16, 0, 0);
}
__device__ inline void vmcnt0() {
    asm volatile("s_waitcnt vmcnt(0)" ::: "memory");
}

// ------------------------------------------------- concat ctx (+bf16 cast)
__global__ __launch_bounds__(256) void concat_cast_kernel(
    const float* __restrict__ hist, const float* __restrict__ cur,
    float* __restrict__ ctx, u16* __restrict__ Xb)
{
    size_t i4 = (size_t)blockIdx.x * 256 + threadIdx.x;
    size_t elem = i4 * 4;
    int c  = (int)(elem & (C - 1));
    size_t rest = elem >> 9;
    int l  = (int)(rest & (L - 1));
    int bh = (int)(rest >> 8);
    int h  = bh & (H - 1);
    int b  = bh >> 3;
    float4 v;
    if (h < HH) {
        size_t off = ((((size_t)b * HH + h) * L + l) * C + c);
        v = *reinterpret_cast<const float4*>(hist + off);
    } else {
        size_t off = (((size_t)b * L + l) * C + c);
        v = *reinterpret_cast<const float4*>(cur + off);
    }
    *reinterpret_cast<float4*>(ctx + elem) = v;
    ushort4 o;
    o.x = f2bf(v.x); o.y = f2bf(v.y); o.z = f2bf(v.z); o.w = f2bf(v.w);
    *reinterpret_cast<ushort4*>(Xb + elem) = o;
}

// ---------------------------------------------------------------- topk+softmax
__global__ void topk_kernel(const float* __restrict__ gmap,
                            float* __restrict__ attnw,
                            int* __restrict__ indxO,
                            int* __restrict__ expertO)
{
    int t = threadIdx.x;
    if (t >= BH) return;
    int h = t & (H - 1);
    const float* row = gmap + (size_t)t * H;
    float v[H];
    #pragma unroll
    for (int j = 0; j < H; ++j) v[j] = row[j];
    float sel[KS]; int si[KS];
    #pragma unroll
    for (int kk = 0; kk < KS; ++kk) {
        float best = -1e30f; int bi = 0;
        #pragma unroll
        for (int j = 0; j < H; ++j) {
            if (v[j] > best) { best = v[j]; bi = j; }
        }
        sel[kk] = best; si[kk] = bi; v[bi] = -1e30f;
    }
    float mx = sel[0];
    float w[KS]; float sum = 0.f;
    #pragma unroll
    for (int kk = 0; kk < KS; ++kk) { w[kk] = __expf(sel[kk] - mx); sum += w[kk]; }
    float inv = 1.f / sum;
    #pragma unroll
    for (int kk = 0; kk < KS; ++kk) {
        attnw[t * KS + kk] = w[kk] * inv;
        indxO[t * KS + kk] = si[kk];
        int e = (si[kk] == h) ? 0 : ((si[kk] > h) ? 2 : 1);
        expertO[t * KS + kk] = e;
    }
}

// ---------------------------------------------------------------- combined bias
__global__ __launch_bounds__(256) void biasc_kernel(
    const float* __restrict__ bo,
    const float* __restrict__ attnw, const int* __restrict__ expertArr,
    float* __restrict__ biasC)
{
    int bh = blockIdx.x;
    float a[KS]; int e[KS];
    #pragma unroll
    for (int k = 0; k < KS; ++k) {
        a[k] = attnw[bh * KS + k];
        e[k] = expertArr[bh * KS + k];
    }
    #pragma unroll
    for (int it = 0; it < 2; ++it) {
        int c = threadIdx.x + it * 256;
        float s = 0.f;
        #pragma unroll
        for (int k = 0; k < KS; ++k)
            s += a[k] * bo[(size_t)e[k] * C + c];
        biasC[(size_t)bh * C + c] = s;
    }
}

// ---------------------------------------------------------------- weight casts
__global__ __launch_bounds__(256) void cast_w_kernel(
    const float* __restrict__ Wq, const float* __restrict__ Wk,
    const float* __restrict__ Wv, u16* __restrict__ Wt)
{
    int p = blockIdx.z;
    int e = p / 3, t = p % 3;
    const float* W = (t == 0 ? Wq : (t == 1 ? Wk : Wv)) + (size_t)e * C * C;
    __shared__ float tile[32][33];
    int k0 = blockIdx.y * 32, n0 = blockIdx.x * 32;
    int tc = threadIdx.x & 31, tr = threadIdx.x >> 5;
    #pragma unroll
    for (int i = 0; i < 4; ++i) {
        int r = tr + i * 8;
        tile[r][tc] = W[(size_t)(k0 + r) * C + n0 + tc];
    }
    __syncthreads();
    #pragma unroll
    for (int i = 0; i < 4; ++i) {
        int r = tr + i * 8;
        Wt[(size_t)p * C * C + (size_t)(n0 + r) * C + k0 + tc] = f2bf(tile[tc][r]);
    }
}

__global__ __launch_bounds__(256) void cast_wo_kernel(
    const float* __restrict__ Wo, u16* __restrict__ Wot)
{
    int p = blockIdx.z;
    const float* W = Wo + (size_t)p * C * C;
    __shared__ float tile[32][33];
    int k0 = blockIdx.y * 32, n0 = blockIdx.x * 32;
    int tc = threadIdx.x & 31, tr = threadIdx.x >> 5;
    #pragma unroll
    for (int i = 0; i < 4; ++i) {
        int r = tr + i * 8;
        tile[r][tc] = W[(size_t)(k0 + r) * C + n0 + tc];
    }
    __syncthreads();
    #pragma unroll
    for (int i = 0; i < 4; ++i) {
        int r = tr + i * 8;
        Wot[(size_t)p * C * C + (size_t)(n0 + r) * C + k0 + tc] = f2bf(tile[tc][r]);
    }
}

// ---------------------------------------------------------------- QKV proj MFMA
// BK=32 double-buffer (32KB total, same as single-buffer BK=64), catalog
// 2-phase recipe: {STAGE(next); compute(cur); vmcnt0; barrier}.
// 64B-row XOR swizzle f(a)=a^(((a>>6)&7)<<4); gload_lds linear dest with
// inverse-swizzled source: r_src = r^((r>>2)&1), s_src = s^(r_src&3).
__global__ __launch_bounds__(256) void proj_mfma(
    const u16* __restrict__ Xb, const u16* __restrict__ Wt,
    const float* __restrict__ bq, const float* __restrict__ bk,
    const float* __restrict__ bv,
    u16* __restrict__ out)
{
    constexpr int BK = 32;
    constexpr int NT = C / BK;   // 16
    int p = blockIdx.z;
    int e = p / 3, t = p % 3;
    const float* bias = (t == 0 ? bq : (t == 1 ? bk : bv)) + (size_t)e * C;
    u16* Y = out + (size_t)p * S;
    const u16* Wp = Wt + (size_t)p * C * C;

    int m0 = blockIdx.y * 128;
    int n0 = blockIdx.x * 128;

    __shared__ u16 As[2][128 * BK];   // 2 x 8KB
    __shared__ u16 Bs[2][128 * BK];   // 2 x 8KB

    int tid  = threadIdx.x;
    int lane = tid & 63;
    int wid  = tid >> 6;
    int wr = wid >> 1, wc = wid & 1;
    int c = lane & 15, gl = lane >> 4;

    f32x4 acc[4][4];
    #pragma unroll
    for (int m = 0; m < 4; ++m)
        #pragma unroll
        for (int n = 0; n < 4; ++n)
            acc[m][n] = (f32x4){0.f, 0.f, 0.f, 0.f};

    int rowA = wr * 64 + c;
    int rowB = wc * 64 + c;

    auto stage = [&](int bb, int kt) {
        int k0 = kt * BK;
        #pragma unroll
        for (int it = 0; it < 2; ++it) {
            int base = it * 256 + wid * 64;       // wave-uniform chunk base
            int ch = base + lane;
            int r = ch >> 2, s = ch & 3;
            int r_src = r ^ ((r >> 2) & 1);
            int s_src = s ^ (r_src & 3);
            gload16(Xb + (size_t)(m0 + r_src) * C + k0 + s_src * 8,
                    &As[bb][base * 8]);
        }
        #pragma unroll
        for (int it = 0; it < 2; ++it) {
            int base = it * 256 + wid * 64;
            int ch = base + lane;
            int r = ch >> 2, s = ch & 3;
            int r_src = r ^ ((r >> 2) & 1);
            int s_src = s ^ (r_src & 3);
            gload16(Wp + (size_t)(n0 + r_src) * C + k0 + s_src * 8,
                    &Bs[bb][base * 8]);
        }
    };

    stage(0, 0);
    vmcnt0();
    __syncthreads();

    for (int kt = 0; kt < NT; ++kt) {
        int bb = kt & 1;
        if (kt + 1 < NT) stage(bb ^ 1, kt + 1);
        const char* Ab = (const char*)&As[bb][0];
        const char* Bb = (const char*)&Bs[bb][0];
        short8 af[4], bfr[4];
        #pragma unroll
        for (int m = 0; m < 4; ++m) {
            int row = rowA + m * 16;
            af[m] = *reinterpret_cast<const short8*>(
                Ab + ((row * 64 + gl * 16) ^ ((row & 7) << 4)));
        }
        #pragma unroll
        for (int n = 0; n < 4; ++n) {
            int row = rowB + n * 16;
            bfr[n] = *reinterpret_cast<const short8*>(
                Bb + ((row * 64 + gl * 16) ^ ((row & 7) << 4)));
        }
        #pragma unroll
        for (int m = 0; m < 4; ++m)
            #pragma unroll
            for (int n = 0; n < 4; ++n)
                acc[m][n] = __builtin_amdgcn_mfma_f32_16x16x32_bf16(
                    af[m], bfr[n], acc[m][n], 0, 0, 0);
        if (kt + 1 < NT) {
            vmcnt0();          // next-tile loads: latency hidden behind compute
            __syncthreads();
        }
    }

    int colb = n0 + wc * 64 + c;
    int rowb = m0 + wr * 64 + gl * 4;
    #pragma unroll
    for (int n = 0; n < 4; ++n) {
        int col = colb + n * 16;
        float bcol = bias[col];
        #pragma unroll
        for (int m = 0; m < 4; ++m) {
            #pragma unroll
            for (int r = 0; r < 4; ++r) {
                int row = rowb + m * 16 + r;
                Y[(size_t)row * C + col] = f2bf(acc[m][n][r] + bcol);
            }
        }
    }
}

// ---------------------------------------------------------------- MFMA flash attention
__global__ __launch_bounds__(256) void attn_mfma(
    const u16* __restrict__ qkv,
    const int* __restrict__ indx, const int* __restrict__ expertArr,
    const float* __restrict__ attnw,
    u16* __restrict__ Obuf)
{
    int head = blockIdx.x;
    int slot = blockIdx.y;
    int z    = blockIdx.z;
    int bh   = z >> 1, qh = z & 1;
    int b    = bh >> 3;
    int mi   = bh * KS + slot;
    int src  = indx[mi];
    int e    = expertArr[mi];
    float ak = attnw[mi];
    int qbase = qh * 128;

    const u16* qp = qkv + (size_t)(e * 3 + 0) * S + (size_t)bh * L * C + head * DH;
    const u16* kp = qkv + (size_t)(e * 3 + 1) * S + (size_t)(b * H + src) * L * C + head * DH;
    const u16* vp = qkv + (size_t)(e * 3 + 2) * S + (size_t)(b * H + src) * L * C + head * DH;

    __shared__ u16 Ks[64 * 64];
    __shared__ u16 Vt[64 * 64];
    __shared__ u16 Pl[4][32 * 64];

    int tid = threadIdx.x, lane = tid & 63, w = tid >> 6;
    int c = lane & 15, gl = lane >> 4;
    int qoff = qbase + w * 32;

    short8 qf[2][2];
    #pragma unroll
    for (int n = 0; n < 2; ++n)
        #pragma unroll
        for (int kf = 0; kf < 2; ++kf)
            qf[n][kf] = *reinterpret_cast<const short8*>(
                qp + (size_t)(qoff + n * 16 + c) * C + kf * 32 + 8 * gl);

    f32x4 accO[4][2];
    #pragma unroll
    for (int m = 0; m < 4; ++m)
        #pragma unroll
        for (int n = 0; n < 2; ++n)
            accO[m][n] = (f32x4){0.f, 0.f, 0.f, 0.f};
    float mrun[2], lrun[2];
    #pragma unroll
    for (int n = 0; n < 2; ++n) { mrun[n] = -1e30f; lrun[n] = 0.f; }

    char* Plw = (char*)&Pl[w][0];

    for (int t = 0; t < 4; ++t) {
        int c0 = t * 64;
        __syncthreads();
        #pragma unroll
        for (int it = 0; it < 2; ++it) {
            int ch = tid + 256 * it;
            int r = ch >> 3, cb = ch & 7;
            short8 kv = *reinterpret_cast<const short8*>(kp + (size_t)(c0 + r) * C + cb * 8);
            int ad = (r * 128 + cb * 16) ^ ((r & 7) << 4);
            *reinterpret_cast<short8*>((char*)Ks + ad) = kv;
        }
        {
            int rp = tid & 31;
            int d0 = (tid >> 5) * 8;
            const u16* v0p = vp + (size_t)(c0 + 2 * rp) * C + d0;
            const u16* v1p = v0p + C;
            ushort4 a0 = *reinterpret_cast<const ushort4*>(v0p);
            ushort4 a1 = *reinterpret_cast<const ushort4*>(v0p + 4);
            ushort4 b0 = *reinterpret_cast<const ushort4*>(v1p);
            ushort4 b1 = *reinterpret_cast<const ushort4*>(v1p + 4);
            u16 va[8] = {a0.x, a0.y, a0.z, a0.w, a1.x, a1.y, a1.z, a1.w};
            u16 vb[8] = {b0.x, b0.y, b0.z, b0.w, b1.x, b1.y, b1.z, b1.w};
            #pragma unroll
            for (int j = 0; j < 8; ++j) {
                u32 pk = ((u32)vb[j] << 16) | (u32)va[j];
                int ad = ((d0 + j) * 128 + rp * 4) ^ (((d0 + j) & 7) << 4);
                *reinterpret_cast<u32*>((char*)Vt + ad) = pk;
            }
        }
        __syncthreads();

        f32x4 accS[4][2];
        #pragma unroll
        for (int m = 0; m < 4; ++m)
            #pragma unroll
            for (int n = 0; n < 2; ++n)
                accS[m][n] = (f32x4){0.f, 0.f, 0.f, 0.f};
        #pragma unroll
        for (int kf = 0; kf < 2; ++kf) {
            short8 ka[4];
            #pragma unroll
            for (int m = 0; m < 4; ++m) {
                int row = m * 16 + c;
                ka[m] = *reinterpret_cast<const short8*>(
                    (char*)Ks + ((row * 128 + (kf * 32 + 8 * gl) * 2) ^ ((row & 7) << 4)));
            }
            #pragma unroll
            for (int m = 0; m < 4; ++m)
                #pragma unroll
                for (int n = 0; n < 2; ++n)
                    accS[m][n] = __builtin_amdgcn_mfma_f32_16x16x32_bf16(
                        ka[m], qf[n][kf], accS[m][n], 0, 0, 0);
        }

        #pragma unroll
        for (int n = 0; n < 2; ++n) {
            float tm = -1e30f;
            #pragma unroll
            for (int m = 0; m < 4; ++m)
                #pragma unroll
                for (int r = 0; r < 4; ++r)
                    tm = fmaxf(tm, accS[m][n][r] * 0.125f);
            tm = fmaxf(tm, __shfl_xor(tm, 16));
            tm = fmaxf(tm, __shfl_xor(tm, 32));
            float nm = fmaxf(mrun[n], tm);
            float al = __expf(mrun[n] - nm);
            mrun[n] = nm;
            lrun[n] *= al;
            #pragma unroll
            for (int m = 0; m < 4; ++m)
                #pragma unroll
                for (int r = 0; r < 4; ++r)
                    accO[m][n][r] *= al;
            float ps = 0.f;
            #pragma unroll
            for (int m = 0; m < 4; ++m)
                #pragma unroll
                for (int r = 0; r < 4; ++r) {
                    float pv = __expf(accS[m][n][r] * 0.125f - nm);
                    accS[m][n][r] = pv;
                    ps += pv;
                }
            lrun[n] += ps;
            int row = n * 16 + c;
            int sw = (row & 7) << 4;
            #pragma unroll
            for (int m = 0; m < 4; ++m) {
                u32 p0 = packbf(accS[m][n][0], accS[m][n][1]);
                u32 p1 = packbf(accS[m][n][2], accS[m][n][3]);
                int base = row * 128 + (m * 16 + 4 * gl) * 2;
                *reinterpret_cast<u32*>(Plw + (base ^ sw)) = p0;
                *reinterpret_cast<u32*>(Plw + ((base + 4) ^ sw)) = p1;
            }
        }

        #pragma unroll
        for (int kf = 0; kf < 2; ++kf) {
            short8 va[4], pb[2];
            #pragma unroll
            for (int m = 0; m < 4; ++m) {
                int row = m * 16 + c;
                va[m] = *reinterpret_cast<const short8*>(
                    (char*)Vt + ((row * 128 + (kf * 32 + 8 * gl) * 2) ^ ((row & 7) << 4)));
            }
            #pragma unroll
            for (int n = 0; n < 2; ++n) {
                int row = n * 16 + c;
                pb[n] = *reinterpret_cast<const short8*>(
                    Plw + ((row * 128 + (kf * 32 + 8 * gl) * 2) ^ ((row & 7) << 4)));
            }
            #pragma unroll
            for (int m = 0; m < 4; ++m)
                #pragma unroll
                for (int n = 0; n < 2; ++n)
                    accO[m][n] = __builtin_amdgcn_mfma_f32_16x16x32_bf16(
                        va[m], pb[n], accO[m][n], 0, 0, 0);
        }
    }

    float inv[2];
    #pragma unroll
    for (int n = 0; n < 2; ++n) {
        float lv = lrun[n];
        lv += __shfl_xor(lv, 16);
        lv += __shfl_xor(lv, 32);
        inv[n] = ak / lv;     // fold a_k into O
    }
    #pragma unroll
    for (int m = 0; m < 4; ++m)
        #pragma unroll
        for (int n = 0; n < 2; ++n) {
            int row = n * 16 + c;
            int sw = (row & 7) << 4;
            float o0 = accO[m][n][0] * inv[n];
            float o1 = accO[m][n][1] * inv[n];
            float o2 = accO[m][n][2] * inv[n];
            float o3 = accO[m][n][3] * inv[n];
            int base = row * 128 + (m * 16 + 4 * gl) * 2;
            *reinterpret_cast<u32*>(Plw + (base ^ sw)) = packbf(o0, o1);
            *reinterpret_cast<u32*>(Plw + ((base + 4) ^ sw)) = packbf(o2, o3);
        }
    #pragma unroll
    for (int it = 0; it < 4; ++it) {
        int q = it * 8 + (lane >> 3), cb = lane & 7;
        short8 ov = *reinterpret_cast<const short8*>(
            Plw + ((q * 128 + cb * 16) ^ ((q & 7) << 4)));
        *reinterpret_cast<short8*>(
            Obuf + ((size_t)mi * L + qoff + q) * C + head * DH + cb * 8) = ov;
    }
}

// ---------------------------------------------------------------- Wo fused-K GEMM + ew epilogue
// wise = [a0 O0|a1 O1|a2 O2|a3 O3] @ [W_e0;W_e1;W_e2;W_e3]  (K=2048)
// epilogue: out = relu(wise + biasC) + xin; also writes bf16 Xb for next proj.
__global__ __launch_bounds__(256) void wo_fused_ew(
    const u16* __restrict__ Obuf, const u16* __restrict__ Wot,
    const int* __restrict__ expertArr, const float* __restrict__ biasC,
    const float* __restrict__ xin,
    float* __restrict__ xout, u16* __restrict__ XbOut)
{
    constexpr int BK = 64;
    int bh = blockIdx.z;
    int m0 = blockIdx.y * 64;
    int n0 = blockIdx.x * 128;

    int e4[KS];
    #pragma unroll
    for (int k = 0; k < KS; ++k) e4[k] = expertArr[bh * KS + k];

    __shared__ u16 As[2][64 * BK];    // 2 x 8KB
    __shared__ u16 Bs[2][128 * BK];   // 2 x 16KB

    int tid = threadIdx.x, lane = tid & 63, wid = tid >> 6;
    int wr = wid >> 1, wc = wid & 1;
    int c = lane & 15, gl = lane >> 4;

    f32x4 acc[2][4];
    #pragma unroll
    for (int m = 0; m < 2; ++m)
        #pragma unroll
        for (int n = 0; n < 4; ++n)
            acc[m][n] = (f32x4){0.f, 0.f, 0.f, 0.f};

    auto stage = [&](int bb, int kt) {
        int slot = kt >> 3;
        int k0   = (kt & 7) * BK;
        const u16* Ap = Obuf + ((size_t)(bh * KS + slot) * L + m0) * C + k0;
        const u16* Bp = Wot + (size_t)e4[slot] * C * C + (size_t)n0 * C + k0;
        #pragma unroll
        for (int it = 0; it < 2; ++it) {
            int base = wid * 64 + it * 256;
            int ch = base + lane;
            int r = ch >> 3, cb = ch & 7;
            int ksw = (cb ^ (r & 7)) << 3;
            gload16(Ap + (size_t)r * C + ksw, &As[bb][base * 8]);
        }
        #pragma unroll
        for (int j = 0; j < 4; ++j) {
            int base = (wid * 4 + j) * 64;
            int ch = base + lane;
            int r = ch >> 3, cb = ch & 7;
            int ksw = (cb ^ (r & 7)) << 3;
            gload16(Bp + (size_t)r * C + ksw, &Bs[bb][base * 8]);
        }
    };

    stage(0, 0);
    vmcnt0();
    __syncthreads();

    constexpr int NT = 4 * (C / BK);   // 32 k-tiles
    for (int kt = 0; kt < NT; ++kt) {
        int bb = kt & 1;
        if (kt + 1 < NT) stage(bb ^ 1, kt + 1);
        const char* Ab = (const char*)&As[bb][0];
        const char* Bb = (const char*)&Bs[bb][0];
        #pragma unroll
        for (int ks = 0; ks < 2; ++ks) {
            int kb2 = (ks * 32 + 8 * gl) * 2;
            short8 af[2], bfr[4];
            #pragma unroll
            for (int m = 0; m < 2; ++m) {
                int row = wr * 32 + m * 16 + c;
                af[m] = *reinterpret_cast<const short8*>(
                    Ab + ((row * 128 + kb2) ^ ((row & 7) << 4)));
            }
            #pragma unroll
            for (int n = 0; n < 4; ++n) {
                int row = wc * 64 + n * 16 + c;
                bfr[n] = *reinterpret_cast<const short8*>(
                    Bb + ((row * 128 + kb2) ^ ((row & 7) << 4)));
            }
            #pragma unroll
            for (int m = 0; m < 2; ++m)
                #pragma unroll
                for (int n = 0; n < 4; ++n)
                    acc[m][n] = __builtin_amdgcn_mfma_f32_16x16x32_bf16(
                        af[m], bfr[n], acc[m][n], 0, 0, 0);
        }
        if (kt + 1 < NT) {
            vmcnt0();
            __syncthreads();
        }
    }

    // ---- fused epilogue: +biasC, relu, +residual, store f32 + bf16
    const float* xr = xin + (size_t)bh * L * C;
    float* xo = xout + (size_t)bh * L * C;
    u16*   xb = XbOut + (size_t)bh * L * C;
    float biasS[4];
    #pragma unroll
    for (int n = 0; n < 4; ++n)
        biasS[n] = biasC[(size_t)bh * C + n0 + wc * 64 + n * 16 + c];
    #pragma unroll
    for (int m = 0; m < 2; ++m) {
        #pragma unroll
        for (int r = 0; r < 4; ++r) {
            int row = m0 + wr * 32 + m * 16 + 4 * gl + r;
            #pragma unroll
            for (int n = 0; n < 4; ++n) {
                int col = n0 + wc * 64 + n * 16 + c;
                float v = acc[m][n][r] + biasS[n];
                float o = fmaxf(v, 0.f) + xr[(size_t)row * C + col];
                xo[(size_t)row * C + col] = o;
                xb[(size_t)row * C + col] = f2bf(o);
            }
        }
    }
}

// ----------------------------------------------------------------------------
extern "C" void kernel_launch(void* const* d_in, const int* in_sizes, int n_in,
                              void* d_out, int out_size, void* d_ws, size_t ws_size,
                              hipStream_t stream) {
    const float* gmap = (const float*)d_in[0];
    const float* hist = (const float*)d_in[1];
    const float* cur  = (const float*)d_in[2];
    const float* Wq   = (const float*)d_in[6];
    const float* bq   = (const float*)d_in[7];
    const float* Wk   = (const float*)d_in[8];
    const float* bk   = (const float*)d_in[9];
    const float* Wv   = (const float*)d_in[10];
    const float* bv   = (const float*)d_in[11];
    const float* Wo   = (const float*)d_in[12];
    const float* bo   = (const float*)d_in[13];
    float* outp       = (float*)d_out;

    char* ws = (char*)d_ws;
    float* ctx  = (float*)(ws);                      // [0,4S)
    float* x1   = (float*)(ws + 4 * S);              // [4S,8S)
    u16*   qkv  = (u16*)(ws + 12 * S);               // [12S,30S)
    u16*   Obuf = (u16*)(ws + 30 * S);               // [30S,38S)
    char*  tail = ws + 38 * S;
    float* attnw  = (float*)(tail);                  // 256 B
    int*   indx   = (int*)(tail + 256);
    int*   expert = (int*)(tail + 512);
    float* biasC  = (float*)(tail + 1024);           // 32 KB
    u16*   Wot    = (u16*)(tail + 64 * 1024);        // 1.57 MB
    u16*   Xb     = (u16*)(tail + 2 * 1024 * 1024);  // 4 MB
    u16*   Wt     = (u16*)(tail + 8 * 1024 * 1024);  // 4.7 MB

    dim3 projGrid(C / 128, M4 / 128, 9);
    dim3 castWGrid(C / 32, C / 32, 9);
    dim3 castWoGrid(C / 32, C / 32, 3);
    dim3 attnGrid(NH, KS, BH * 2);
    dim3 woGrid(C / 128, L / 64, BH);                // 256 blocks
    int ewBlocks = (int)(S / 4 / 256);   // 2048

    concat_cast_kernel<<<ewBlocks, 256, 0, stream>>>(hist, cur, ctx, Xb);
    topk_kernel<<<1, 64, 0, stream>>>(gmap, attnw, indx, expert);
    biasc_kernel<<<BH, 256, 0, stream>>>(bo, attnw, expert, biasC);
    cast_wo_kernel<<<castWoGrid, 256, 0, stream>>>(Wo, Wot);
    cast_w_kernel<<<castWGrid, 256, 0, stream>>>(Wq, Wk, Wv, Wt);

    // ---- layer 1: ctx -> x1 (+Xb for layer-2 proj)
    proj_mfma<<<projGrid, 256, 0, stream>>>(Xb, Wt, bq, bk, bv, qkv);
    attn_mfma<<<attnGrid, 256, 0, stream>>>(qkv, indx, expert, attnw, Obuf);
    wo_fused_ew<<<woGrid, 256, 0, stream>>>(Obuf, Wot, expert, biasC, ctx, x1, Xb);

    // ---- layer 2: x1 -> out
    proj_mfma<<<projGrid, 256, 0, stream>>>(Xb, Wt, bq, bk, bv, qkv);
    attn_mfma<<<attnGrid, 256, 0, stream>>>(qkv, indx, expert, attnw, Obuf);
    wo_fused_ew<<<woGrid, 256, 0, stream>>>(Obuf, Wot, expert, biasC, x1, outp, Xb);
}

// Round 8
// 179.258 us; speedup vs baseline: 1.5179x; 1.0454x over previous
//
#include <hip/hip_runtime.h>
#include <hip/hip_bf16.h>

// Problem dims
constexpr int B   = 2;
constexpr int HH  = 7;    // history turns
constexpr int H   = 8;    // total turns
constexpr int L   = 256;
constexpr int C   = 512;
constexpr int NH  = 8;
constexpr int DH  = 64;
constexpr int KS  = 4;    // top-k slots
constexpr int BH  = B * H;          // 16
constexpr int M4  = B * H * L;      // 4096 rows
constexpr size_t S = (size_t)B * H * L * C;  // 2,097,152 elems

typedef __attribute__((ext_vector_type(8))) short short8;
typedef __attribute__((ext_vector_type(4))) float f32x4;
typedef unsigned short u16;
typedef unsigned int u32;

__device__ inline float bf2f(u16 u) {
    u32 x = ((u32)u) << 16;
    return __uint_as_float(x);
}
__device__ inline u16 f2bf(float f) {
    __hip_bfloat16 h = __float2bfloat16(f);
    return *reinterpret_cast<u16*>(&h);
}
__device__ inline u32 packbf(float lo, float hi) {
    return ((u32)f2bf(hi) << 16) | (u32)f2bf(lo);
}
__device__ inline void gload16(const void* g, void* l) {
    __builtin_amdgcn_global_load_lds(
        (const __attribute__((address_space(1))) void*)g,
        (__attribute__((address_space(3))) void*)l,
        16, 0, 0);
}
__device__ inline void vmcnt0() {
    asm volatile("s_waitcnt vmcnt(0)" ::: "memory");
}
__device__ inline void vmcnt4() {
    asm volatile("s_waitcnt vmcnt(4)" ::: "memory");
}

// ------------------------------------------------- concat ctx (+bf16 cast)
__global__ __launch_bounds__(256) void concat_cast_kernel(
    const float* __restrict__ hist, const float* __restrict__ cur,
    float* __restrict__ ctx, u16* __restrict__ Xb)
{
    size_t i4 = (size_t)blockIdx.x * 256 + threadIdx.x;
    size_t elem = i4 * 4;
    int c  = (int)(elem & (C - 1));
    size_t rest = elem >> 9;
    int l  = (int)(rest & (L - 1));
    int bh = (int)(rest >> 8);
    int h  = bh & (H - 1);
    int b  = bh >> 3;
    float4 v;
    if (h < HH) {
        size_t off = ((((size_t)b * HH + h) * L + l) * C + c);
        v = *reinterpret_cast<const float4*>(hist + off);
    } else {
        size_t off = (((size_t)b * L + l) * C + c);
        v = *reinterpret_cast<const float4*>(cur + off);
    }
    *reinterpret_cast<float4*>(ctx + elem) = v;
    ushort4 o;
    o.x = f2bf(v.x); o.y = f2bf(v.y); o.z = f2bf(v.z); o.w = f2bf(v.w);
    *reinterpret_cast<ushort4*>(Xb + elem) = o;
}

// ---------------------------------------------------------------- topk+softmax
__global__ void topk_kernel(const float* __restrict__ gmap,
                            float* __restrict__ attnw,
                            int* __restrict__ indxO,
                            int* __restrict__ expertO)
{
    int t = threadIdx.x;
    if (t >= BH) return;
    int h = t & (H - 1);
    const float* row = gmap + (size_t)t * H;
    float v[H];
    #pragma unroll
    for (int j = 0; j < H; ++j) v[j] = row[j];
    float sel[KS]; int si[KS];
    #pragma unroll
    for (int kk = 0; kk < KS; ++kk) {
        float best = -1e30f; int bi = 0;
        #pragma unroll
        for (int j = 0; j < H; ++j) {
            if (v[j] > best) { best = v[j]; bi = j; }
        }
        sel[kk] = best; si[kk] = bi; v[bi] = -1e30f;
    }
    float mx = sel[0];
    float w[KS]; float sum = 0.f;
    #pragma unroll
    for (int kk = 0; kk < KS; ++kk) { w[kk] = __expf(sel[kk] - mx); sum += w[kk]; }
    float inv = 1.f / sum;
    #pragma unroll
    for (int kk = 0; kk < KS; ++kk) {
        attnw[t * KS + kk] = w[kk] * inv;
        indxO[t * KS + kk] = si[kk];
        int e = (si[kk] == h) ? 0 : ((si[kk] > h) ? 2 : 1);
        expertO[t * KS + kk] = e;
    }
}

// ---------------------------------------------------------------- combined bias
__global__ __launch_bounds__(256) void biasc_kernel(
    const float* __restrict__ bo,
    const float* __restrict__ attnw, const int* __restrict__ expertArr,
    float* __restrict__ biasC)
{
    int bh = blockIdx.x;
    float a[KS]; int e[KS];
    #pragma unroll
    for (int k = 0; k < KS; ++k) {
        a[k] = attnw[bh * KS + k];
        e[k] = expertArr[bh * KS + k];
    }
    #pragma unroll
    for (int it = 0; it < 2; ++it) {
        int c = threadIdx.x + it * 256;
        float s = 0.f;
        #pragma unroll
        for (int k = 0; k < KS; ++k)
            s += a[k] * bo[(size_t)e[k] * C + c];
        biasC[(size_t)bh * C + c] = s;
    }
}

// ---------------------------------------------------------------- weight casts
__global__ __launch_bounds__(256) void cast_w_kernel(
    const float* __restrict__ Wq, const float* __restrict__ Wk,
    const float* __restrict__ Wv, u16* __restrict__ Wt)
{
    int p = blockIdx.z;
    int e = p / 3, t = p % 3;
    const float* W = (t == 0 ? Wq : (t == 1 ? Wk : Wv)) + (size_t)e * C * C;
    __shared__ float tile[32][33];
    int k0 = blockIdx.y * 32, n0 = blockIdx.x * 32;
    int tc = threadIdx.x & 31, tr = threadIdx.x >> 5;
    #pragma unroll
    for (int i = 0; i < 4; ++i) {
        int r = tr + i * 8;
        tile[r][tc] = W[(size_t)(k0 + r) * C + n0 + tc];
    }
    __syncthreads();
    #pragma unroll
    for (int i = 0; i < 4; ++i) {
        int r = tr + i * 8;
        Wt[(size_t)p * C * C + (size_t)(n0 + r) * C + k0 + tc] = f2bf(tile[tc][r]);
    }
}

__global__ __launch_bounds__(256) void cast_wo_kernel(
    const float* __restrict__ Wo, u16* __restrict__ Wot)
{
    int p = blockIdx.z;
    const float* W = Wo + (size_t)p * C * C;
    __shared__ float tile[32][33];
    int k0 = blockIdx.y * 32, n0 = blockIdx.x * 32;
    int tc = threadIdx.x & 31, tr = threadIdx.x >> 5;
    #pragma unroll
    for (int i = 0; i < 4; ++i) {
        int r = tr + i * 8;
        tile[r][tc] = W[(size_t)(k0 + r) * C + n0 + tc];
    }
    __syncthreads();
    #pragma unroll
    for (int i = 0; i < 4; ++i) {
        int r = tr + i * 8;
        Wot[(size_t)p * C * C + (size_t)(n0 + r) * C + k0 + tc] = f2bf(tile[tc][r]);
    }
}

// ---------------------------------------------------------------- QKV proj MFMA
// BK=32 double-buffer + T4 counted vmcnt: {stage(t+1); vmcnt(4); bar;
// compute(t); bar} — the wait targets tile t (issued one iter ago), so
// tile t+1's loads stay in flight across both barriers.
__global__ __launch_bounds__(256) void proj_mfma(
    const u16* __restrict__ Xb, const u16* __restrict__ Wt,
    const float* __restrict__ bq, const float* __restrict__ bk,
    const float* __restrict__ bv,
    u16* __restrict__ out)
{
    constexpr int BK = 32;
    constexpr int NT = C / BK;   // 16
    int p = blockIdx.z;
    int e = p / 3, t = p % 3;
    const float* bias = (t == 0 ? bq : (t == 1 ? bk : bv)) + (size_t)e * C;
    u16* Y = out + (size_t)p * S;
    const u16* Wp = Wt + (size_t)p * C * C;

    int m0 = blockIdx.y * 128;
    int n0 = blockIdx.x * 128;

    __shared__ u16 As[2][128 * BK];   // 2 x 8KB
    __shared__ u16 Bs[2][128 * BK];   // 2 x 8KB

    int tid  = threadIdx.x;
    int lane = tid & 63;
    int wid  = tid >> 6;
    int wr = wid >> 1, wc = wid & 1;
    int c = lane & 15, gl = lane >> 4;

    f32x4 acc[4][4];
    #pragma unroll
    for (int m = 0; m < 4; ++m)
        #pragma unroll
        for (int n = 0; n < 4; ++n)
            acc[m][n] = (f32x4){0.f, 0.f, 0.f, 0.f};

    int rowA = wr * 64 + c;
    int rowB = wc * 64 + c;

    auto stage = [&](int bb, int kt) {
        int k0 = kt * BK;
        #pragma unroll
        for (int it = 0; it < 2; ++it) {
            int base = it * 256 + wid * 64;       // wave-uniform chunk base
            int ch = base + lane;
            int r = ch >> 2, s = ch & 3;
            int r_src = r ^ ((r >> 2) & 1);
            int s_src = s ^ (r_src & 3);
            gload16(Xb + (size_t)(m0 + r_src) * C + k0 + s_src * 8,
                    &As[bb][base * 8]);
        }
        #pragma unroll
        for (int it = 0; it < 2; ++it) {
            int base = it * 256 + wid * 64;
            int ch = base + lane;
            int r = ch >> 2, s = ch & 3;
            int r_src = r ^ ((r >> 2) & 1);
            int s_src = s ^ (r_src & 3);
            gload16(Wp + (size_t)(n0 + r_src) * C + k0 + s_src * 8,
                    &Bs[bb][base * 8]);
        }
    };

    stage(0, 0);

    for (int kt = 0; kt < NT; ++kt) {
        int bb = kt & 1;
        if (kt + 1 < NT) {
            stage(bb ^ 1, kt + 1);   // 4 loads -> in flight across barriers
            vmcnt4();                // wait only for tile kt's 4 loads
        } else {
            vmcnt0();
        }
        __syncthreads();
        const char* Ab = (const char*)&As[bb][0];
        const char* Bb = (const char*)&Bs[bb][0];
        short8 af[4], bfr[4];
        #pragma unroll
        for (int m = 0; m < 4; ++m) {
            int row = rowA + m * 16;
            af[m] = *reinterpret_cast<const short8*>(
                Ab + ((row * 64 + gl * 16) ^ ((row & 7) << 4)));
        }
        #pragma unroll
        for (int n = 0; n < 4; ++n) {
            int row = rowB + n * 16;
            bfr[n] = *reinterpret_cast<const short8*>(
                Bb + ((row * 64 + gl * 16) ^ ((row & 7) << 4)));
        }
        #pragma unroll
        for (int m = 0; m < 4; ++m)
            #pragma unroll
            for (int n = 0; n < 4; ++n)
                acc[m][n] = __builtin_amdgcn_mfma_f32_16x16x32_bf16(
                    af[m], bfr[n], acc[m][n], 0, 0, 0);
        if (kt + 1 < NT) __syncthreads();   // seal reads before next stage overwrites
    }

    int colb = n0 + wc * 64 + c;
    int rowb = m0 + wr * 64 + gl * 4;
    #pragma unroll
    for (int n = 0; n < 4; ++n) {
        int col = colb + n * 16;
        float bcol = bias[col];
        #pragma unroll
        for (int m = 0; m < 4; ++m) {
            #pragma unroll
            for (int r = 0; r < 4; ++r) {
                int row = rowb + m * 16 + r;
                Y[(size_t)row * C + col] = f2bf(acc[m][n][r] + bcol);
            }
        }
    }
}

// ---------------------------------------------------------------- MFMA flash attention
__global__ __launch_bounds__(256) void attn_mfma(
    const u16* __restrict__ qkv,
    const int* __restrict__ indx, const int* __restrict__ expertArr,
    const float* __restrict__ attnw,
    u16* __restrict__ Obuf)
{
    int head = blockIdx.x;
    int slot = blockIdx.y;
    int z    = blockIdx.z;
    int bh   = z >> 1, qh = z & 1;
    int b    = bh >> 3;
    int mi   = bh * KS + slot;
    int src  = indx[mi];
    int e    = expertArr[mi];
    float ak = attnw[mi];
    int qbase = qh * 128;

    const u16* qp = qkv + (size_t)(e * 3 + 0) * S + (size_t)bh * L * C + head * DH;
    const u16* kp = qkv + (size_t)(e * 3 + 1) * S + (size_t)(b * H + src) * L * C + head * DH;
    const u16* vp = qkv + (size_t)(e * 3 + 2) * S + (size_t)(b * H + src) * L * C + head * DH;

    __shared__ u16 Ks[64 * 64];
    __shared__ u16 Vt[64 * 64];
    __shared__ u16 Pl[4][32 * 64];

    int tid = threadIdx.x, lane = tid & 63, w = tid >> 6;
    int c = lane & 15, gl = lane >> 4;
    int qoff = qbase + w * 32;

    short8 qf[2][2];
    #pragma unroll
    for (int n = 0; n < 2; ++n)
        #pragma unroll
        for (int kf = 0; kf < 2; ++kf)
            qf[n][kf] = *reinterpret_cast<const short8*>(
                qp + (size_t)(qoff + n * 16 + c) * C + kf * 32 + 8 * gl);

    f32x4 accO[4][2];
    #pragma unroll
    for (int m = 0; m < 4; ++m)
        #pragma unroll
        for (int n = 0; n < 2; ++n)
            accO[m][n] = (f32x4){0.f, 0.f, 0.f, 0.f};
    float mrun[2], lrun[2];
    #pragma unroll
    for (int n = 0; n < 2; ++n) { mrun[n] = -1e30f; lrun[n] = 0.f; }

    char* Plw = (char*)&Pl[w][0];

    for (int t = 0; t < 4; ++t) {
        int c0 = t * 64;
        __syncthreads();
        #pragma unroll
        for (int it = 0; it < 2; ++it) {
            int ch = tid + 256 * it;
            int r = ch >> 3, cb = ch & 7;
            short8 kv = *reinterpret_cast<const short8*>(kp + (size_t)(c0 + r) * C + cb * 8);
            int ad = (r * 128 + cb * 16) ^ ((r & 7) << 4);
            *reinterpret_cast<short8*>((char*)Ks + ad) = kv;
        }
        {
            int rp = tid & 31;
            int d0 = (tid >> 5) * 8;
            const u16* v0p = vp + (size_t)(c0 + 2 * rp) * C + d0;
            const u16* v1p = v0p + C;
            ushort4 a0 = *reinterpret_cast<const ushort4*>(v0p);
            ushort4 a1 = *reinterpret_cast<const ushort4*>(v0p + 4);
            ushort4 b0 = *reinterpret_cast<const ushort4*>(v1p);
            ushort4 b1 = *reinterpret_cast<const ushort4*>(v1p + 4);
            u16 va[8] = {a0.x, a0.y, a0.z, a0.w, a1.x, a1.y, a1.z, a1.w};
            u16 vb[8] = {b0.x, b0.y, b0.z, b0.w, b1.x, b1.y, b1.z, b1.w};
            #pragma unroll
            for (int j = 0; j < 8; ++j) {
                u32 pk = ((u32)vb[j] << 16) | (u32)va[j];
                int ad = ((d0 + j) * 128 + rp * 4) ^ (((d0 + j) & 7) << 4);
                *reinterpret_cast<u32*>((char*)Vt + ad) = pk;
            }
        }
        __syncthreads();

        f32x4 accS[4][2];
        #pragma unroll
        for (int m = 0; m < 4; ++m)
            #pragma unroll
            for (int n = 0; n < 2; ++n)
                accS[m][n] = (f32x4){0.f, 0.f, 0.f, 0.f};
        #pragma unroll
        for (int kf = 0; kf < 2; ++kf) {
            short8 ka[4];
            #pragma unroll
            for (int m = 0; m < 4; ++m) {
                int row = m * 16 + c;
                ka[m] = *reinterpret_cast<const short8*>(
                    (char*)Ks + ((row * 128 + (kf * 32 + 8 * gl) * 2) ^ ((row & 7) << 4)));
            }
            #pragma unroll
            for (int m = 0; m < 4; ++m)
                #pragma unroll
                for (int n = 0; n < 2; ++n)
                    accS[m][n] = __builtin_amdgcn_mfma_f32_16x16x32_bf16(
                        ka[m], qf[n][kf], accS[m][n], 0, 0, 0);
        }

        #pragma unroll
        for (int n = 0; n < 2; ++n) {
            float tm = -1e30f;
            #pragma unroll
            for (int m = 0; m < 4; ++m)
                #pragma unroll
                for (int r = 0; r < 4; ++r)
                    tm = fmaxf(tm, accS[m][n][r] * 0.125f);
            tm = fmaxf(tm, __shfl_xor(tm, 16));
            tm = fmaxf(tm, __shfl_xor(tm, 32));
            float nm = fmaxf(mrun[n], tm);
            float al = __expf(mrun[n] - nm);
            mrun[n] = nm;
            lrun[n] *= al;
            #pragma unroll
            for (int m = 0; m < 4; ++m)
                #pragma unroll
                for (int r = 0; r < 4; ++r)
                    accO[m][n][r] *= al;
            float ps = 0.f;
            #pragma unroll
            for (int m = 0; m < 4; ++m)
                #pragma unroll
                for (int r = 0; r < 4; ++r) {
                    float pv = __expf(accS[m][n][r] * 0.125f - nm);
                    accS[m][n][r] = pv;
                    ps += pv;
                }
            lrun[n] += ps;
            int row = n * 16 + c;
            int sw = (row & 7) << 4;
            #pragma unroll
            for (int m = 0; m < 4; ++m) {
                u32 p0 = packbf(accS[m][n][0], accS[m][n][1]);
                u32 p1 = packbf(accS[m][n][2], accS[m][n][3]);
                int base = row * 128 + (m * 16 + 4 * gl) * 2;
                *reinterpret_cast<u32*>(Plw + (base ^ sw)) = p0;
                *reinterpret_cast<u32*>(Plw + ((base + 4) ^ sw)) = p1;
            }
        }

        #pragma unroll
        for (int kf = 0; kf < 2; ++kf) {
            short8 va[4], pb[2];
            #pragma unroll
            for (int m = 0; m < 4; ++m) {
                int row = m * 16 + c;
                va[m] = *reinterpret_cast<const short8*>(
                    (char*)Vt + ((row * 128 + (kf * 32 + 8 * gl) * 2) ^ ((row & 7) << 4)));
            }
            #pragma unroll
            for (int n = 0; n < 2; ++n) {
                int row = n * 16 + c;
                pb[n] = *reinterpret_cast<const short8*>(
                    Plw + ((row * 128 + (kf * 32 + 8 * gl) * 2) ^ ((row & 7) << 4)));
            }
            #pragma unroll
            for (int m = 0; m < 4; ++m)
                #pragma unroll
                for (int n = 0; n < 2; ++n)
                    accO[m][n] = __builtin_amdgcn_mfma_f32_16x16x32_bf16(
                        va[m], pb[n], accO[m][n], 0, 0, 0);
        }
    }

    float inv[2];
    #pragma unroll
    for (int n = 0; n < 2; ++n) {
        float lv = lrun[n];
        lv += __shfl_xor(lv, 16);
        lv += __shfl_xor(lv, 32);
        inv[n] = ak / lv;     // fold a_k into O
    }
    #pragma unroll
    for (int m = 0; m < 4; ++m)
        #pragma unroll
        for (int n = 0; n < 2; ++n) {
            int row = n * 16 + c;
            int sw = (row & 7) << 4;
            float o0 = accO[m][n][0] * inv[n];
            float o1 = accO[m][n][1] * inv[n];
            float o2 = accO[m][n][2] * inv[n];
            float o3 = accO[m][n][3] * inv[n];
            int base = row * 128 + (m * 16 + 4 * gl) * 2;
            *reinterpret_cast<u32*>(Plw + (base ^ sw)) = packbf(o0, o1);
            *reinterpret_cast<u32*>(Plw + ((base + 4) ^ sw)) = packbf(o2, o3);
        }
    #pragma unroll
    for (int it = 0; it < 4; ++it) {
        int q = it * 8 + (lane >> 3), cb = lane & 7;
        short8 ov = *reinterpret_cast<const short8*>(
            Plw + ((q * 128 + cb * 16) ^ ((q & 7) << 4)));
        *reinterpret_cast<short8*>(
            Obuf + ((size_t)mi * L + qoff + q) * C + head * DH + cb * 8) = ov;
    }
}

// ---------------------------------------------------------------- Wo fused-K GEMM + ew epilogue
// 64x64 tiles -> 512 blocks (2/CU), 32KB LDS; counted vmcnt(4) pipeline.
// wise = [a0 O0|a1 O1|a2 O2|a3 O3] @ [W_e0;W_e1;W_e2;W_e3]  (K=2048)
// epilogue: out = relu(wise + biasC) + xin; writes f32 xout + bf16 Xb.
__global__ __launch_bounds__(256) void wo_fused_ew(
    const u16* __restrict__ Obuf, const u16* __restrict__ Wot,
    const int* __restrict__ expertArr, const float* __restrict__ biasC,
    const float* __restrict__ xin,
    float* __restrict__ xout, u16* __restrict__ XbOut)
{
    constexpr int BK = 64;
    int bh = blockIdx.z;
    int m0 = blockIdx.y * 64;
    int n0 = blockIdx.x * 64;

    int e4[KS];
    #pragma unroll
    for (int k = 0; k < KS; ++k) e4[k] = expertArr[bh * KS + k];

    __shared__ u16 As[2][64 * BK];    // 2 x 8KB
    __shared__ u16 Bs[2][64 * BK];    // 2 x 8KB

    int tid = threadIdx.x, lane = tid & 63, wid = tid >> 6;
    int wr = wid >> 1, wc = wid & 1;   // 2x2 waves of 32x32
    int c = lane & 15, gl = lane >> 4;

    f32x4 acc[2][2];
    #pragma unroll
    for (int m = 0; m < 2; ++m)
        #pragma unroll
        for (int n = 0; n < 2; ++n)
            acc[m][n] = (f32x4){0.f, 0.f, 0.f, 0.f};

    auto stage = [&](int bb, int kt) {
        int slot = kt >> 3;
        int k0   = (kt & 7) * BK;
        const u16* Ap = Obuf + ((size_t)(bh * KS + slot) * L + m0) * C + k0;
        const u16* Bp = Wot + (size_t)e4[slot] * C * C + (size_t)n0 * C + k0;
        #pragma unroll
        for (int it = 0; it < 2; ++it) {
            int base = wid * 64 + it * 256;
            int ch = base + lane;
            int r = ch >> 3, cb = ch & 7;
            int ksw = (cb ^ (r & 7)) << 3;
            gload16(Ap + (size_t)r * C + ksw, &As[bb][base * 8]);
        }
        #pragma unroll
        for (int it = 0; it < 2; ++it) {
            int base = wid * 64 + it * 256;
            int ch = base + lane;
            int r = ch >> 3, cb = ch & 7;
            int ksw = (cb ^ (r & 7)) << 3;
            gload16(Bp + (size_t)r * C + ksw, &Bs[bb][base * 8]);
        }
    };

    stage(0, 0);

    constexpr int NT = 4 * (C / BK);   // 32 k-tiles
    for (int kt = 0; kt < NT; ++kt) {
        int bb = kt & 1;
        if (kt + 1 < NT) {
            stage(bb ^ 1, kt + 1);
            vmcnt4();                // wait for tile kt only
        } else {
            vmcnt0();
        }
        __syncthreads();
        const char* Ab = (const char*)&As[bb][0];
        const char* Bb = (const char*)&Bs[bb][0];
        #pragma unroll
        for (int ks = 0; ks < 2; ++ks) {
            int kb2 = (ks * 32 + 8 * gl) * 2;
            short8 af[2], bfr[2];
            #pragma unroll
            for (int m = 0; m < 2; ++m) {
                int row = wr * 32 + m * 16 + c;
                af[m] = *reinterpret_cast<const short8*>(
                    Ab + ((row * 128 + kb2) ^ ((row & 7) << 4)));
            }
            #pragma unroll
            for (int n = 0; n < 2; ++n) {
                int row = wc * 32 + n * 16 + c;
                bfr[n] = *reinterpret_cast<const short8*>(
                    Bb + ((row * 128 + kb2) ^ ((row & 7) << 4)));
            }
            #pragma unroll
            for (int m = 0; m < 2; ++m)
                #pragma unroll
                for (int n = 0; n < 2; ++n)
                    acc[m][n] = __builtin_amdgcn_mfma_f32_16x16x32_bf16(
                        af[m], bfr[n], acc[m][n], 0, 0, 0);
        }
        if (kt + 1 < NT) __syncthreads();
    }

    // ---- fused epilogue: +biasC, relu, +residual, store f32 + bf16
    const float* xr = xin + (size_t)bh * L * C;
    float* xo = xout + (size_t)bh * L * C;
    u16*   xb = XbOut + (size_t)bh * L * C;
    float biasS[2];
    #pragma unroll
    for (int n = 0; n < 2; ++n)
        biasS[n] = biasC[(size_t)bh * C + n0 + wc * 32 + n * 16 + c];
    #pragma unroll
    for (int m = 0; m < 2; ++m) {
        #pragma unroll
        for (int r = 0; r < 4; ++r) {
            int row = m0 + wr * 32 + m * 16 + 4 * gl + r;
            #pragma unroll
            for (int n = 0; n < 2; ++n) {
                int col = n0 + wc * 32 + n * 16 + c;
                float v = acc[m][n][r] + biasS[n];
                float o = fmaxf(v, 0.f) + xr[(size_t)row * C + col];
                xo[(size_t)row * C + col] = o;
                xb[(size_t)row * C + col] = f2bf(o);
            }
        }
    }
}

// ----------------------------------------------------------------------------
extern "C" void kernel_launch(void* const* d_in, const int* in_sizes, int n_in,
                              void* d_out, int out_size, void* d_ws, size_t ws_size,
                              hipStream_t stream) {
    const float* gmap = (const float*)d_in[0];
    const float* hist = (const float*)d_in[1];
    const float* cur  = (const float*)d_in[2];
    const float* Wq   = (const float*)d_in[6];
    const float* bq   = (const float*)d_in[7];
    const float* Wk   = (const float*)d_in[8];
    const float* bk   = (const float*)d_in[9];
    const float* Wv   = (const float*)d_in[10];
    const float* bv   = (const float*)d_in[11];
    const float* Wo   = (const float*)d_in[12];
    const float* bo   = (const float*)d_in[13];
    float* outp       = (float*)d_out;

    char* ws = (char*)d_ws;
    float* ctx  = (float*)(ws);                      // [0,4S)
    float* x1   = (float*)(ws + 4 * S);              // [4S,8S)
    u16*   qkv  = (u16*)(ws + 12 * S);               // [12S,30S)
    u16*   Obuf = (u16*)(ws + 30 * S);               // [30S,38S)
    char*  tail = ws + 38 * S;
    float* attnw  = (float*)(tail);                  // 256 B
    int*   indx   = (int*)(tail + 256);
    int*   expert = (int*)(tail + 512);
    float* biasC  = (float*)(tail + 1024);           // 32 KB
    u16*   Wot    = (u16*)(tail + 64 * 1024);        // 1.57 MB
    u16*   Xb     = (u16*)(tail + 2 * 1024 * 1024);  // 4 MB
    u16*   Wt     = (u16*)(tail + 8 * 1024 * 1024);  // 4.7 MB

    dim3 projGrid(C / 128, M4 / 128, 9);
    dim3 castWGrid(C / 32, C / 32, 9);
    dim3 castWoGrid(C / 32, C / 32, 3);
    dim3 attnGrid(NH, KS, BH * 2);
    dim3 woGrid(C / 64, L / 64, BH);                 // 8 x 4 x 16 = 512 blocks
    int ewBlocks = (int)(S / 4 / 256);   // 2048

    concat_cast_kernel<<<ewBlocks, 256, 0, stream>>>(hist, cur, ctx, Xb);
    topk_kernel<<<1, 64, 0, stream>>>(gmap, attnw, indx, expert);
    biasc_kernel<<<BH, 256, 0, stream>>>(bo, attnw, expert, biasC);
    cast_wo_kernel<<<castWoGrid, 256, 0, stream>>>(Wo, Wot);
    cast_w_kernel<<<castWGrid, 256, 0, stream>>>(Wq, Wk, Wv, Wt);

    // ---- layer 1: ctx -> x1 (+Xb for layer-2 proj)
    proj_mfma<<<projGrid, 256, 0, stream>>>(Xb, Wt, bq, bk, bv, qkv);
    attn_mfma<<<attnGrid, 256, 0, stream>>>(qkv, indx, expert, attnw, Obuf);
    wo_fused_ew<<<woGrid, 256, 0, stream>>>(Obuf, Wot, expert, biasC, ctx, x1, Xb);

    // ---- layer 2: x1 -> out
    proj_mfma<<<projGrid, 256, 0, stream>>>(Xb, Wt, bq, bk, bv, qkv);
    attn_mfma<<<attnGrid, 256, 0, stream>>>(qkv, indx, expert, attnw, Obuf);
    wo_fused_ew<<<woGrid, 256, 0, stream>>>(Obuf, Wot, expert, biasC, x1, outp, Xb);
}

// Round 9
// 173.707 us; speedup vs baseline: 1.5664x; 1.0320x over previous
//
#include <hip/hip_runtime.h>
#include <hip/hip_bf16.h>

// Problem dims
constexpr int B   = 2;
constexpr int HH  = 7;    // history turns
constexpr int H   = 8;    // total turns
constexpr int L   = 256;
constexpr int C   = 512;
constexpr int NH  = 8;
constexpr int DH  = 64;
constexpr int KS  = 4;    // top-k slots
constexpr int BH  = B * H;          // 16
constexpr int M4  = B * H * L;      // 4096 rows
constexpr size_t S = (size_t)B * H * L * C;  // 2,097,152 elems

typedef __attribute__((ext_vector_type(8))) short short8;
typedef __attribute__((ext_vector_type(4))) float f32x4;
typedef unsigned short u16;
typedef unsigned int u32;

__device__ inline float bf2f(u16 u) {
    u32 x = ((u32)u) << 16;
    return __uint_as_float(x);
}
__device__ inline u16 f2bf(float f) {
    __hip_bfloat16 h = __float2bfloat16(f);
    return *reinterpret_cast<u16*>(&h);
}
__device__ inline u32 packbf(float lo, float hi) {
    return ((u32)f2bf(hi) << 16) | (u32)f2bf(lo);
}
__device__ inline void gload16(const void* g, void* l) {
    __builtin_amdgcn_global_load_lds(
        (const __attribute__((address_space(1))) void*)g,
        (__attribute__((address_space(3))) void*)l,
        16, 0, 0);
}
__device__ inline void vmcnt0() {
    asm volatile("s_waitcnt vmcnt(0)" ::: "memory");
}
__device__ inline void vmcnt4() {
    asm volatile("s_waitcnt vmcnt(4)" ::: "memory");
}

// ------------------------------------------------- concat ctx (+bf16 cast)
__global__ __launch_bounds__(256) void concat_cast_kernel(
    const float* __restrict__ hist, const float* __restrict__ cur,
    float* __restrict__ ctx, u16* __restrict__ Xb)
{
    size_t i4 = (size_t)blockIdx.x * 256 + threadIdx.x;
    size_t elem = i4 * 4;
    int c  = (int)(elem & (C - 1));
    size_t rest = elem >> 9;
    int l  = (int)(rest & (L - 1));
    int bh = (int)(rest >> 8);
    int h  = bh & (H - 1);
    int b  = bh >> 3;
    float4 v;
    if (h < HH) {
        size_t off = ((((size_t)b * HH + h) * L + l) * C + c);
        v = *reinterpret_cast<const float4*>(hist + off);
    } else {
        size_t off = (((size_t)b * L + l) * C + c);
        v = *reinterpret_cast<const float4*>(cur + off);
    }
    *reinterpret_cast<float4*>(ctx + elem) = v;
    ushort4 o;
    o.x = f2bf(v.x); o.y = f2bf(v.y); o.z = f2bf(v.z); o.w = f2bf(v.w);
    *reinterpret_cast<ushort4*>(Xb + elem) = o;
}

// ---------------------------------------------------------------- topk+softmax
__global__ void topk_kernel(const float* __restrict__ gmap,
                            float* __restrict__ attnw,
                            int* __restrict__ indxO,
                            int* __restrict__ expertO)
{
    int t = threadIdx.x;
    if (t >= BH) return;
    int h = t & (H - 1);
    const float* row = gmap + (size_t)t * H;
    float v[H];
    #pragma unroll
    for (int j = 0; j < H; ++j) v[j] = row[j];
    float sel[KS]; int si[KS];
    #pragma unroll
    for (int kk = 0; kk < KS; ++kk) {
        float best = -1e30f; int bi = 0;
        #pragma unroll
        for (int j = 0; j < H; ++j) {
            if (v[j] > best) { best = v[j]; bi = j; }
        }
        sel[kk] = best; si[kk] = bi; v[bi] = -1e30f;
    }
    float mx = sel[0];
    float w[KS]; float sum = 0.f;
    #pragma unroll
    for (int kk = 0; kk < KS; ++kk) { w[kk] = __expf(sel[kk] - mx); sum += w[kk]; }
    float inv = 1.f / sum;
    #pragma unroll
    for (int kk = 0; kk < KS; ++kk) {
        attnw[t * KS + kk] = w[kk] * inv;
        indxO[t * KS + kk] = si[kk];
        int e = (si[kk] == h) ? 0 : ((si[kk] > h) ? 2 : 1);
        expertO[t * KS + kk] = e;
    }
}

// ---------------------------------------------------------------- combined bias
__global__ __launch_bounds__(256) void biasc_kernel(
    const float* __restrict__ bo,
    const float* __restrict__ attnw, const int* __restrict__ expertArr,
    float* __restrict__ biasC)
{
    int bh = blockIdx.x;
    float a[KS]; int e[KS];
    #pragma unroll
    for (int k = 0; k < KS; ++k) {
        a[k] = attnw[bh * KS + k];
        e[k] = expertArr[bh * KS + k];
    }
    #pragma unroll
    for (int it = 0; it < 2; ++it) {
        int c = threadIdx.x + it * 256;
        float s = 0.f;
        #pragma unroll
        for (int k = 0; k < KS; ++k)
            s += a[k] * bo[(size_t)e[k] * C + c];
        biasC[(size_t)bh * C + c] = s;
    }
}

// ---------------------------------------------------------------- weight casts
__global__ __launch_bounds__(256) void cast_w_kernel(
    const float* __restrict__ Wq, const float* __restrict__ Wk,
    const float* __restrict__ Wv, u16* __restrict__ Wt)
{
    int p = blockIdx.z;
    int e = p / 3, t = p % 3;
    const float* W = (t == 0 ? Wq : (t == 1 ? Wk : Wv)) + (size_t)e * C * C;
    __shared__ float tile[32][33];
    int k0 = blockIdx.y * 32, n0 = blockIdx.x * 32;
    int tc = threadIdx.x & 31, tr = threadIdx.x >> 5;
    #pragma unroll
    for (int i = 0; i < 4; ++i) {
        int r = tr + i * 8;
        tile[r][tc] = W[(size_t)(k0 + r) * C + n0 + tc];
    }
    __syncthreads();
    #pragma unroll
    for (int i = 0; i < 4; ++i) {
        int r = tr + i * 8;
        Wt[(size_t)p * C * C + (size_t)(n0 + r) * C + k0 + tc] = f2bf(tile[tc][r]);
    }
}

__global__ __launch_bounds__(256) void cast_wo_kernel(
    const float* __restrict__ Wo, u16* __restrict__ Wot)
{
    int p = blockIdx.z;
    const float* W = Wo + (size_t)p * C * C;
    __shared__ float tile[32][33];
    int k0 = blockIdx.y * 32, n0 = blockIdx.x * 32;
    int tc = threadIdx.x & 31, tr = threadIdx.x >> 5;
    #pragma unroll
    for (int i = 0; i < 4; ++i) {
        int r = tr + i * 8;
        tile[r][tc] = W[(size_t)(k0 + r) * C + n0 + tc];
    }
    __syncthreads();
    #pragma unroll
    for (int i = 0; i < 4; ++i) {
        int r = tr + i * 8;
        Wot[(size_t)p * C * C + (size_t)(n0 + r) * C + k0 + tc] = f2bf(tile[tc][r]);
    }
}

// ---------------------------------------------------------------- QKV proj MFMA
// R8 structure + XCD-locality remap: flat grid 1152; XCD x receives
// gwi = x*144..x*144+143 (HW maps blockIdx%8 -> XCD), so each XCD serves
// ~1 plane: L2 working set = X (4MB) + W_p (0.5MB) -> A/B re-reads L2-hit.
__global__ __launch_bounds__(256) void proj_mfma(
    const u16* __restrict__ Xb, const u16* __restrict__ Wt,
    const float* __restrict__ bq, const float* __restrict__ bk,
    const float* __restrict__ bv,
    u16* __restrict__ out)
{
    constexpr int BK = 32;
    constexpr int NT = C / BK;   // 16
    int bid  = blockIdx.x;            // 0..1151
    int xcd  = bid & 7;
    int slot = bid >> 3;              // 0..143
    int gwi  = xcd * 144 + slot;
    int p    = gwi >> 7;              // /128 -> plane
    int wp   = gwi & 127;
    int n0   = (wp & 3) * 128;
    int m0   = (wp >> 2) * 128;

    int e = p / 3, t = p % 3;
    const float* bias = (t == 0 ? bq : (t == 1 ? bk : bv)) + (size_t)e * C;
    u16* Y = out + (size_t)p * S;
    const u16* Wp = Wt + (size_t)p * C * C;

    __shared__ u16 As[2][128 * BK];   // 2 x 8KB
    __shared__ u16 Bs[2][128 * BK];   // 2 x 8KB

    int tid  = threadIdx.x;
    int lane = tid & 63;
    int wid  = tid >> 6;
    int wr = wid >> 1, wc = wid & 1;
    int c = lane & 15, gl = lane >> 4;

    f32x4 acc[4][4];
    #pragma unroll
    for (int m = 0; m < 4; ++m)
        #pragma unroll
        for (int n = 0; n < 4; ++n)
            acc[m][n] = (f32x4){0.f, 0.f, 0.f, 0.f};

    int rowA = wr * 64 + c;
    int rowB = wc * 64 + c;

    auto stage = [&](int bb, int kt) {
        int k0 = kt * BK;
        #pragma unroll
        for (int it = 0; it < 2; ++it) {
            int base = it * 256 + wid * 64;       // wave-uniform chunk base
            int ch = base + lane;
            int r = ch >> 2, s = ch & 3;
            int r_src = r ^ ((r >> 2) & 1);
            int s_src = s ^ (r_src & 3);
            gload16(Xb + (size_t)(m0 + r_src) * C + k0 + s_src * 8,
                    &As[bb][base * 8]);
        }
        #pragma unroll
        for (int it = 0; it < 2; ++it) {
            int base = it * 256 + wid * 64;
            int ch = base + lane;
            int r = ch >> 2, s = ch & 3;
            int r_src = r ^ ((r >> 2) & 1);
            int s_src = s ^ (r_src & 3);
            gload16(Wp + (size_t)(n0 + r_src) * C + k0 + s_src * 8,
                    &Bs[bb][base * 8]);
        }
    };

    stage(0, 0);

    for (int kt = 0; kt < NT; ++kt) {
        int bb = kt & 1;
        if (kt + 1 < NT) {
            stage(bb ^ 1, kt + 1);   // 4 loads -> in flight across barriers
            vmcnt4();                // wait only for tile kt's 4 loads
        } else {
            vmcnt0();
        }
        __syncthreads();
        const char* Ab = (const char*)&As[bb][0];
        const char* Bb = (const char*)&Bs[bb][0];
        short8 af[4], bfr[4];
        #pragma unroll
        for (int m = 0; m < 4; ++m) {
            int row = rowA + m * 16;
            af[m] = *reinterpret_cast<const short8*>(
                Ab + ((row * 64 + gl * 16) ^ ((row & 7) << 4)));
        }
        #pragma unroll
        for (int n = 0; n < 4; ++n) {
            int row = rowB + n * 16;
            bfr[n] = *reinterpret_cast<const short8*>(
                Bb + ((row * 64 + gl * 16) ^ ((row & 7) << 4)));
        }
        #pragma unroll
        for (int m = 0; m < 4; ++m)
            #pragma unroll
            for (int n = 0; n < 4; ++n)
                acc[m][n] = __builtin_amdgcn_mfma_f32_16x16x32_bf16(
                    af[m], bfr[n], acc[m][n], 0, 0, 0);
        if (kt + 1 < NT) __syncthreads();   // seal reads before next stage overwrites
    }

    int colb = n0 + wc * 64 + c;
    int rowb = m0 + wr * 64 + gl * 4;
    #pragma unroll
    for (int n = 0; n < 4; ++n) {
        int col = colb + n * 16;
        float bcol = bias[col];
        #pragma unroll
        for (int m = 0; m < 4; ++m) {
            #pragma unroll
            for (int r = 0; r < 4; ++r) {
                int row = rowb + m * 16 + r;
                Y[(size_t)row * C + col] = f2bf(acc[m][n][r] + bcol);
            }
        }
    }
}

// ---------------------------------------------------------------- MFMA flash attention
__global__ __launch_bounds__(256) void attn_mfma(
    const u16* __restrict__ qkv,
    const int* __restrict__ indx, const int* __restrict__ expertArr,
    const float* __restrict__ attnw,
    u16* __restrict__ Obuf)
{
    int head = blockIdx.x;
    int slot = blockIdx.y;
    int z    = blockIdx.z;
    int bh   = z >> 1, qh = z & 1;
    int b    = bh >> 3;
    int mi   = bh * KS + slot;
    int src  = indx[mi];
    int e    = expertArr[mi];
    float ak = attnw[mi];
    int qbase = qh * 128;

    const u16* qp = qkv + (size_t)(e * 3 + 0) * S + (size_t)bh * L * C + head * DH;
    const u16* kp = qkv + (size_t)(e * 3 + 1) * S + (size_t)(b * H + src) * L * C + head * DH;
    const u16* vp = qkv + (size_t)(e * 3 + 2) * S + (size_t)(b * H + src) * L * C + head * DH;

    __shared__ u16 Ks[64 * 64];
    __shared__ u16 Vt[64 * 64];
    __shared__ u16 Pl[4][32 * 64];

    int tid = threadIdx.x, lane = tid & 63, w = tid >> 6;
    int c = lane & 15, gl = lane >> 4;
    int qoff = qbase + w * 32;

    short8 qf[2][2];
    #pragma unroll
    for (int n = 0; n < 2; ++n)
        #pragma unroll
        for (int kf = 0; kf < 2; ++kf)
            qf[n][kf] = *reinterpret_cast<const short8*>(
                qp + (size_t)(qoff + n * 16 + c) * C + kf * 32 + 8 * gl);

    f32x4 accO[4][2];
    #pragma unroll
    for (int m = 0; m < 4; ++m)
        #pragma unroll
        for (int n = 0; n < 2; ++n)
            accO[m][n] = (f32x4){0.f, 0.f, 0.f, 0.f};
    float mrun[2], lrun[2];
    #pragma unroll
    for (int n = 0; n < 2; ++n) { mrun[n] = -1e30f; lrun[n] = 0.f; }

    char* Plw = (char*)&Pl[w][0];

    for (int t = 0; t < 4; ++t) {
        int c0 = t * 64;
        __syncthreads();
        #pragma unroll
        for (int it = 0; it < 2; ++it) {
            int ch = tid + 256 * it;
            int r = ch >> 3, cb = ch & 7;
            short8 kv = *reinterpret_cast<const short8*>(kp + (size_t)(c0 + r) * C + cb * 8);
            int ad = (r * 128 + cb * 16) ^ ((r & 7) << 4);
            *reinterpret_cast<short8*>((char*)Ks + ad) = kv;
        }
        {
            int rp = tid & 31;
            int d0 = (tid >> 5) * 8;
            const u16* v0p = vp + (size_t)(c0 + 2 * rp) * C + d0;
            const u16* v1p = v0p + C;
            ushort4 a0 = *reinterpret_cast<const ushort4*>(v0p);
            ushort4 a1 = *reinterpret_cast<const ushort4*>(v0p + 4);
            ushort4 b0 = *reinterpret_cast<const ushort4*>(v1p);
            ushort4 b1 = *reinterpret_cast<const ushort4*>(v1p + 4);
            u16 va[8] = {a0.x, a0.y, a0.z, a0.w, a1.x, a1.y, a1.z, a1.w};
            u16 vb[8] = {b0.x, b0.y, b0.z, b0.w, b1.x, b1.y, b1.z, b1.w};
            #pragma unroll
            for (int j = 0; j < 8; ++j) {
                u32 pk = ((u32)vb[j] << 16) | (u32)va[j];
                int ad = ((d0 + j) * 128 + rp * 4) ^ (((d0 + j) & 7) << 4);
                *reinterpret_cast<u32*>((char*)Vt + ad) = pk;
            }
        }
        __syncthreads();

        f32x4 accS[4][2];
        #pragma unroll
        for (int m = 0; m < 4; ++m)
            #pragma unroll
            for (int n = 0; n < 2; ++n)
                accS[m][n] = (f32x4){0.f, 0.f, 0.f, 0.f};
        #pragma unroll
        for (int kf = 0; kf < 2; ++kf) {
            short8 ka[4];
            #pragma unroll
            for (int m = 0; m < 4; ++m) {
                int row = m * 16 + c;
                ka[m] = *reinterpret_cast<const short8*>(
                    (char*)Ks + ((row * 128 + (kf * 32 + 8 * gl) * 2) ^ ((row & 7) << 4)));
            }
            #pragma unroll
            for (int m = 0; m < 4; ++m)
                #pragma unroll
                for (int n = 0; n < 2; ++n)
                    accS[m][n] = __builtin_amdgcn_mfma_f32_16x16x32_bf16(
                        ka[m], qf[n][kf], accS[m][n], 0, 0, 0);
        }

        #pragma unroll
        for (int n = 0; n < 2; ++n) {
            float tm = -1e30f;
            #pragma unroll
            for (int m = 0; m < 4; ++m)
                #pragma unroll
                for (int r = 0; r < 4; ++r)
                    tm = fmaxf(tm, accS[m][n][r] * 0.125f);
            tm = fmaxf(tm, __shfl_xor(tm, 16));
            tm = fmaxf(tm, __shfl_xor(tm, 32));
            float nm = fmaxf(mrun[n], tm);
            float al = __expf(mrun[n] - nm);
            mrun[n] = nm;
            lrun[n] *= al;
            #pragma unroll
            for (int m = 0; m < 4; ++m)
                #pragma unroll
                for (int r = 0; r < 4; ++r)
                    accO[m][n][r] *= al;
            float ps = 0.f;
            #pragma unroll
            for (int m = 0; m < 4; ++m)
                #pragma unroll
                for (int r = 0; r < 4; ++r) {
                    float pv = __expf(accS[m][n][r] * 0.125f - nm);
                    accS[m][n][r] = pv;
                    ps += pv;
                }
            lrun[n] += ps;
            int row = n * 16 + c;
            int sw = (row & 7) << 4;
            #pragma unroll
            for (int m = 0; m < 4; ++m) {
                u32 p0 = packbf(accS[m][n][0], accS[m][n][1]);
                u32 p1 = packbf(accS[m][n][2], accS[m][n][3]);
                int base = row * 128 + (m * 16 + 4 * gl) * 2;
                *reinterpret_cast<u32*>(Plw + (base ^ sw)) = p0;
                *reinterpret_cast<u32*>(Plw + ((base + 4) ^ sw)) = p1;
            }
        }

        #pragma unroll
        for (int kf = 0; kf < 2; ++kf) {
            short8 va[4], pb[2];
            #pragma unroll
            for (int m = 0; m < 4; ++m) {
                int row = m * 16 + c;
                va[m] = *reinterpret_cast<const short8*>(
                    (char*)Vt + ((row * 128 + (kf * 32 + 8 * gl) * 2) ^ ((row & 7) << 4)));
            }
            #pragma unroll
            for (int n = 0; n < 2; ++n) {
                int row = n * 16 + c;
                pb[n] = *reinterpret_cast<const short8*>(
                    Plw + ((row * 128 + (kf * 32 + 8 * gl) * 2) ^ ((row & 7) << 4)));
            }
            #pragma unroll
            for (int m = 0; m < 4; ++m)
                #pragma unroll
                for (int n = 0; n < 2; ++n)
                    accO[m][n] = __builtin_amdgcn_mfma_f32_16x16x32_bf16(
                        va[m], pb[n], accO[m][n], 0, 0, 0);
        }
    }

    float inv[2];
    #pragma unroll
    for (int n = 0; n < 2; ++n) {
        float lv = lrun[n];
        lv += __shfl_xor(lv, 16);
        lv += __shfl_xor(lv, 32);
        inv[n] = ak / lv;     // fold a_k into O
    }
    #pragma unroll
    for (int m = 0; m < 4; ++m)
        #pragma unroll
        for (int n = 0; n < 2; ++n) {
            int row = n * 16 + c;
            int sw = (row & 7) << 4;
            float o0 = accO[m][n][0] * inv[n];
            float o1 = accO[m][n][1] * inv[n];
            float o2 = accO[m][n][2] * inv[n];
            float o3 = accO[m][n][3] * inv[n];
            int base = row * 128 + (m * 16 + 4 * gl) * 2;
            *reinterpret_cast<u32*>(Plw + (base ^ sw)) = packbf(o0, o1);
            *reinterpret_cast<u32*>(Plw + ((base + 4) ^ sw)) = packbf(o2, o3);
        }
    #pragma unroll
    for (int it = 0; it < 4; ++it) {
        int q = it * 8 + (lane >> 3), cb = lane & 7;
        short8 ov = *reinterpret_cast<const short8*>(
            Plw + ((q * 128 + cb * 16) ^ ((q & 7) << 4)));
        *reinterpret_cast<short8*>(
            Obuf + ((size_t)mi * L + qoff + q) * C + head * DH + cb * 8) = ov;
    }
}

// ---------------------------------------------------------------- Wo fused-K GEMM + ew epilogue
// 64x64 tiles, counted vmcnt pipeline, + XCD-locality remap: XCD x gets
// gwi = x*64..x*64+63 -> 2 bh per XCD (Obuf 2MB + Wot 1.5MB fits L2).
__global__ __launch_bounds__(256) void wo_fused_ew(
    const u16* __restrict__ Obuf, const u16* __restrict__ Wot,
    const int* __restrict__ expertArr, const float* __restrict__ biasC,
    const float* __restrict__ xin,
    float* __restrict__ xout, u16* __restrict__ XbOut)
{
    constexpr int BK = 64;
    int bid  = blockIdx.x;             // 0..511
    int xcd  = bid & 7;
    int slot = bid >> 3;               // 0..63
    int gwi  = xcd * 64 + slot;
    int bh   = gwi >> 5;
    int wp   = gwi & 31;
    int n0   = (wp & 7) * 64;
    int m0   = (wp >> 3) * 64;

    int e4[KS];
    #pragma unroll
    for (int k = 0; k < KS; ++k) e4[k] = expertArr[bh * KS + k];

    __shared__ u16 As[2][64 * BK];    // 2 x 8KB
    __shared__ u16 Bs[2][64 * BK];    // 2 x 8KB

    int tid = threadIdx.x, lane = tid & 63, wid = tid >> 6;
    int wr = wid >> 1, wc = wid & 1;   // 2x2 waves of 32x32
    int c = lane & 15, gl = lane >> 4;

    f32x4 acc[2][2];
    #pragma unroll
    for (int m = 0; m < 2; ++m)
        #pragma unroll
        for (int n = 0; n < 2; ++n)
            acc[m][n] = (f32x4){0.f, 0.f, 0.f, 0.f};

    auto stage = [&](int bb, int kt) {
        int kslot = kt >> 3;
        int k0    = (kt & 7) * BK;
        const u16* Ap = Obuf + ((size_t)(bh * KS + kslot) * L + m0) * C + k0;
        const u16* Bp = Wot + (size_t)e4[kslot] * C * C + (size_t)n0 * C + k0;
        #pragma unroll
        for (int it = 0; it < 2; ++it) {
            int base = wid * 64 + it * 256;
            int ch = base + lane;
            int r = ch >> 3, cb = ch & 7;
            int ksw = (cb ^ (r & 7)) << 3;
            gload16(Ap + (size_t)r * C + ksw, &As[bb][base * 8]);
        }
        #pragma unroll
        for (int it = 0; it < 2; ++it) {
            int base = wid * 64 + it * 256;
            int ch = base + lane;
            int r = ch >> 3, cb = ch & 7;
            int ksw = (cb ^ (r & 7)) << 3;
            gload16(Bp + (size_t)r * C + ksw, &Bs[bb][base * 8]);
        }
    };

    stage(0, 0);

    constexpr int NT = 4 * (C / BK);   // 32 k-tiles
    for (int kt = 0; kt < NT; ++kt) {
        int bb = kt & 1;
        if (kt + 1 < NT) {
            stage(bb ^ 1, kt + 1);
            vmcnt4();                // wait for tile kt only
        } else {
            vmcnt0();
        }
        __syncthreads();
        const char* Ab = (const char*)&As[bb][0];
        const char* Bb = (const char*)&Bs[bb][0];
        #pragma unroll
        for (int ks = 0; ks < 2; ++ks) {
            int kb2 = (ks * 32 + 8 * gl) * 2;
            short8 af[2], bfr[2];
            #pragma unroll
            for (int m = 0; m < 2; ++m) {
                int row = wr * 32 + m * 16 + c;
                af[m] = *reinterpret_cast<const short8*>(
                    Ab + ((row * 128 + kb2) ^ ((row & 7) << 4)));
            }
            #pragma unroll
            for (int n = 0; n < 2; ++n) {
                int row = wc * 32 + n * 16 + c;
                bfr[n] = *reinterpret_cast<const short8*>(
                    Bb + ((row * 128 + kb2) ^ ((row & 7) << 4)));
            }
            #pragma unroll
            for (int m = 0; m < 2; ++m)
                #pragma unroll
                for (int n = 0; n < 2; ++n)
                    acc[m][n] = __builtin_amdgcn_mfma_f32_16x16x32_bf16(
                        af[m], bfr[n], acc[m][n], 0, 0, 0);
        }
        if (kt + 1 < NT) __syncthreads();
    }

    // ---- fused epilogue: +biasC, relu, +residual, store f32 + bf16
    const float* xr = xin + (size_t)bh * L * C;
    float* xo = xout + (size_t)bh * L * C;
    u16*   xb = XbOut + (size_t)bh * L * C;
    float biasS[2];
    #pragma unroll
    for (int n = 0; n < 2; ++n)
        biasS[n] = biasC[(size_t)bh * C + n0 + wc * 32 + n * 16 + c];
    #pragma unroll
    for (int m = 0; m < 2; ++m) {
        #pragma unroll
        for (int r = 0; r < 4; ++r) {
            int row = m0 + wr * 32 + m * 16 + 4 * gl + r;
            #pragma unroll
            for (int n = 0; n < 2; ++n) {
                int col = n0 + wc * 32 + n * 16 + c;
                float v = acc[m][n][r] + biasS[n];
                float o = fmaxf(v, 0.f) + xr[(size_t)row * C + col];
                xo[(size_t)row * C + col] = o;
                xb[(size_t)row * C + col] = f2bf(o);
            }
        }
    }
}

// ----------------------------------------------------------------------------
extern "C" void kernel_launch(void* const* d_in, const int* in_sizes, int n_in,
                              void* d_out, int out_size, void* d_ws, size_t ws_size,
                              hipStream_t stream) {
    const float* gmap = (const float*)d_in[0];
    const float* hist = (const float*)d_in[1];
    const float* cur  = (const float*)d_in[2];
    const float* Wq   = (const float*)d_in[6];
    const float* bq   = (const float*)d_in[7];
    const float* Wk   = (const float*)d_in[8];
    const float* bk   = (const float*)d_in[9];
    const float* Wv   = (const float*)d_in[10];
    const float* bv   = (const float*)d_in[11];
    const float* Wo   = (const float*)d_in[12];
    const float* bo   = (const float*)d_in[13];
    float* outp       = (float*)d_out;

    char* ws = (char*)d_ws;
    float* ctx  = (float*)(ws);                      // [0,4S)
    float* x1   = (float*)(ws + 4 * S);              // [4S,8S)
    u16*   qkv  = (u16*)(ws + 12 * S);               // [12S,30S)
    u16*   Obuf = (u16*)(ws + 30 * S);               // [30S,38S)
    char*  tail = ws + 38 * S;
    float* attnw  = (float*)(tail);                  // 256 B
    int*   indx   = (int*)(tail + 256);
    int*   expert = (int*)(tail + 512);
    float* biasC  = (float*)(tail + 1024);           // 32 KB
    u16*   Wot    = (u16*)(tail + 64 * 1024);        // 1.57 MB
    u16*   Xb     = (u16*)(tail + 2 * 1024 * 1024);  // 4 MB
    u16*   Wt     = (u16*)(tail + 8 * 1024 * 1024);  // 4.7 MB

    dim3 castWGrid(C / 32, C / 32, 9);
    dim3 castWoGrid(C / 32, C / 32, 3);
    dim3 attnGrid(NH, KS, BH * 2);
    int projBlocks = (C / 128) * (M4 / 128) * 9;     // 1152, flat + remap
    int woBlocks   = (C / 64) * (L / 64) * BH;       // 512, flat + remap
    int ewBlocks = (int)(S / 4 / 256);   // 2048

    concat_cast_kernel<<<ewBlocks, 256, 0, stream>>>(hist, cur, ctx, Xb);
    topk_kernel<<<1, 64, 0, stream>>>(gmap, attnw, indx, expert);
    biasc_kernel<<<BH, 256, 0, stream>>>(bo, attnw, expert, biasC);
    cast_wo_kernel<<<castWoGrid, 256, 0, stream>>>(Wo, Wot);
    cast_w_kernel<<<castWGrid, 256, 0, stream>>>(Wq, Wk, Wv, Wt);

    // ---- layer 1: ctx -> x1 (+Xb for layer-2 proj)
    proj_mfma<<<projBlocks, 256, 0, stream>>>(Xb, Wt, bq, bk, bv, qkv);
    attn_mfma<<<attnGrid, 256, 0, stream>>>(qkv, indx, expert, attnw, Obuf);
    wo_fused_ew<<<woBlocks, 256, 0, stream>>>(Obuf, Wot, expert, biasC, ctx, x1, Xb);

    // ---- layer 2: x1 -> out
    proj_mfma<<<projBlocks, 256, 0, stream>>>(Xb, Wt, bq, bk, bv, qkv);
    attn_mfma<<<attnGrid, 256, 0, stream>>>(qkv, indx, expert, attnw, Obuf);
    wo_fused_ew<<<woBlocks, 256, 0, stream>>>(Obuf, Wot, expert, biasC, x1, outp, Xb);
}